// Round 5
// baseline (266.962 us; speedup 1.0000x reference)
//
#include <hip/hip_runtime.h>
#include <hip/hip_bf16.h>
#include <math.h>

#define L_SEQ 1024
#define D_DIM 512
#define A_DIM 32
#define H_DIM 8
#define F_DIM 2048
#define AH 256
#define DH 4096
#define NC 16
#define CH 64
#define QKN 512
#define EPS_LN 1e-5f

typedef __attribute__((ext_vector_type(8))) short short8;
typedef __attribute__((ext_vector_type(4))) float floatx4;

#define ASYNC_COPY16(gp, lp)                                                     \
    __builtin_amdgcn_global_load_lds(                                            \
        (const __attribute__((address_space(1))) void*)(const void*)(gp),        \
        (__attribute__((address_space(3))) void*)(void*)(lp), 16, 0, 0)

// ---------------------------------------------------------------------------
// prep: fused LN0 (+bf16 casts of x) and all weight transpose/converts.
// ---------------------------------------------------------------------------
__global__ __launch_bounds__(256) void prep_kernel(const float* __restrict__ x,
                                                   const float* __restrict__ ln0w,
                                                   const float* __restrict__ ln0b,
                                                   const float* __restrict__ qw,
                                                   const float* __restrict__ kw,
                                                   const float* __restrict__ vw,
                                                   const float* __restrict__ w1,
                                                   const float* __restrict__ w2,
                                                   __hip_bfloat16* __restrict__ xn,
                                                   __hip_bfloat16* __restrict__ xb,
                                                   __hip_bfloat16* __restrict__ qkwt,
                                                   __hip_bfloat16* __restrict__ vwt,
                                                   __hip_bfloat16* __restrict__ w1t,
                                                   __hip_bfloat16* __restrict__ w2t) {
    __shared__ float tt[32][33];
    __shared__ float red[8];
    int bid = blockIdx.x;
    int tid = threadIdx.x;
    if (bid < 1024) {
        int l = bid;
        float v0 = x[l * D_DIM + tid];
        float v1 = x[l * D_DIM + 256 + tid];
        float s = v0 + v1, s2 = v0 * v0 + v1 * v1;
        for (int off = 32; off > 0; off >>= 1) {
            s += __shfl_down(s, off);
            s2 += __shfl_down(s2, off);
        }
        int lane = tid & 63, wid = tid >> 6;
        if (lane == 0) { red[wid] = s; red[4 + wid] = s2; }
        __syncthreads();
        float ts = red[0] + red[1] + red[2] + red[3];
        float t2 = red[4] + red[5] + red[6] + red[7];
        float mu = ts / (float)D_DIM;
        float var = t2 / (float)D_DIM - mu * mu;
        float rs = rsqrtf(var + EPS_LN);
        xn[l * D_DIM + tid]       = (__hip_bfloat16)((v0 - mu) * rs * ln0w[tid] + ln0b[tid]);
        xn[l * D_DIM + 256 + tid] = (__hip_bfloat16)((v1 - mu) * rs * ln0w[256 + tid] + ln0b[256 + tid]);
        xb[l * D_DIM + tid]       = (__hip_bfloat16)v0;
        xb[l * D_DIM + 256 + tid] = (__hip_bfloat16)v1;
        return;
    }
    const float* in;
    __hip_bfloat16* out;
    int R, C, mode = 0, t;
    if (bid < 1152)      { t = bid - 1024;  in = qw; out = qkwt;                      R = 512;  C = 256; }
    else if (bid < 1280) { t = bid - 1152;  in = kw; out = qkwt + (size_t)AH * D_DIM; R = 512;  C = 256; }
    else if (bid < 3328) { t = bid - 1280;  in = vw; out = vwt;  mode = 1;            R = 512;  C = 4096; }
    else if (bid < 11520){ t = bid - 3328;  in = w1; out = w1t;                       R = 4096; C = 2048; }
    else                 { t = bid - 11520; in = w2; out = w2t;                       R = 2048; C = 512; }
    int ctiles = C >> 5;
    int cx = t % ctiles, cy = t / ctiles;
    int tx = tid & 31, ti = tid >> 5;
    int r0 = cy * 32, c0 = cx * 32;
#pragma unroll
    for (int ii = 0; ii < 4; ++ii)
        tt[ti + ii * 8][tx] = in[(size_t)(r0 + ti + ii * 8) * C + c0 + tx];
    __syncthreads();
#pragma unroll
    for (int ii = 0; ii < 4; ++ii) {
        int c = c0 + ti + ii * 8;
        int orow = mode ? (((c & 7) << 9) | (c >> 3)) : c;
        out[(size_t)orow * R + r0 + tx] = (__hip_bfloat16)tt[tx][ti + ii * 8];
    }
}

// ---------------------------------------------------------------------------
// Shared BK=128 MFMA core. As/Bs: 64 rows x 128 elems, 16-chunk XOR swizzle.
// ---------------------------------------------------------------------------
__device__ __forceinline__ void gemm_core(const __hip_bfloat16* __restrict__ A,
                                          const __hip_bfloat16* __restrict__ Bt,
                                          int K, int bm, int bn, int k_beg, int k_end,
                                          __hip_bfloat16* As, __hip_bfloat16* Bs,
                                          floatx4 acc[2][2]) {
    const int tid = threadIdx.x;
    const int w = tid >> 6, lane = tid & 63;
    const int wm = (w >> 1) * 32, wn = (w & 1) * 32;
    const int quad = lane >> 4, l16 = lane & 15;
    const int srow = tid >> 4, sslot = tid & 15;
    const int scg = sslot ^ srow;  // srow in 0..15
    for (int k0 = k_beg; k0 < k_end; k0 += 128) {
        __syncthreads();
#pragma unroll
        for (int j = 0; j < 4; ++j) {
            ASYNC_COPY16(A + (size_t)(bm + j * 16 + srow) * K + k0 + scg * 8,
                         As + j * 2048 + w * 512);
            ASYNC_COPY16(Bt + (size_t)(bn + j * 16 + srow) * K + k0 + scg * 8,
                         Bs + j * 2048 + w * 512);
        }
        __syncthreads();
#pragma unroll
        for (int ks = 0; ks < 4; ++ks) {
            short8 af[2], bfr[2];
#pragma unroll
            for (int mt = 0; mt < 2; ++mt) {
                int rr = wm + mt * 16 + l16;
                af[mt] = *(const short8*)(As + rr * 128 + (((ks * 4 + quad) ^ (rr & 15)) * 8));
            }
#pragma unroll
            for (int nt = 0; nt < 2; ++nt) {
                int rr = wn + nt * 16 + l16;
                bfr[nt] = *(const short8*)(Bs + rr * 128 + (((ks * 4 + quad) ^ (rr & 15)) * 8));
            }
#pragma unroll
            for (int mt = 0; mt < 2; ++mt)
#pragma unroll
                for (int nt = 0; nt < 2; ++nt)
                    acc[mt][nt] = __builtin_amdgcn_mfma_f32_16x16x32_bf16(
                        af[mt], bfr[nt], acc[mt][nt], 0, 0, 0);
        }
    }
}

// ---------------------------------------------------------------------------
// Fused q|k and v projections in one dispatch.
// blocks [0,1024): v (strip=8)  -> bf16 [l][h*D+d], perm bias
// blocks [1024,1152): qk        -> fp32 exp(clip(+qb|kb))
// ---------------------------------------------------------------------------
__global__ __launch_bounds__(256) void qkv_gemm(const __hip_bfloat16* __restrict__ xn,
                                                const __hip_bfloat16* __restrict__ xb,
                                                const __hip_bfloat16* __restrict__ qkwt,
                                                const __hip_bfloat16* __restrict__ vwt,
                                                const float* __restrict__ qb,
                                                const float* __restrict__ kb,
                                                const float* __restrict__ vb,
                                                float* __restrict__ qk,
                                                __hip_bfloat16* __restrict__ v) {
    __shared__ __align__(16) __hip_bfloat16 As[64 * 128];
    __shared__ __align__(16) __hip_bfloat16 Bs[64 * 128];
    const int tid = threadIdx.x;
    const int w = tid >> 6, lane = tid & 63;
    const int wm = (w >> 1) * 32, wn = (w & 1) * 32;
    const int quad = lane >> 4, l16 = lane & 15;
    int bid = blockIdx.x;
    bool isv = bid < 1024;
    const __hip_bfloat16 *A, *Bt;
    int bx, by;
    if (isv) {
        int r = bid >> 3;
        bx = (bid & 7) * 8 + (r & 7);
        by = r >> 3;
        A = xb; Bt = vwt;
    } else {
        int b2 = bid - 1024;
        bx = b2 & 7; by = b2 >> 3;
        A = xn; Bt = qkwt;
    }
    const int bm = by * 64, bn = bx * 64;
    floatx4 acc[2][2];
#pragma unroll
    for (int i = 0; i < 2; ++i)
#pragma unroll
        for (int j = 0; j < 2; ++j) acc[i][j] = (floatx4)0.f;
    gemm_core(A, Bt, D_DIM, bm, bn, 0, D_DIM, As, Bs, acc);
#pragma unroll
    for (int mt = 0; mt < 2; ++mt)
#pragma unroll
        for (int nt = 0; nt < 2; ++nt)
#pragma unroll
            for (int r = 0; r < 4; ++r) {
                int row = bm + wm + mt * 16 + quad * 4 + r;
                int col = bn + wn + nt * 16 + l16;
                float val = acc[mt][nt][r];
                if (isv) {
                    int bi = ((col & 511) << 3) | (col >> 9);
                    v[(size_t)row * DH + col] = (__hip_bfloat16)(val + vb[bi]);
                } else {
                    float bb = (col < 256) ? qb[col] : kb[col - 256];
                    qk[(size_t)row * QKN + col] = expf(fminf(fmaxf(val + bb, -10.f), 10.f));
                }
            }
}

// ---------------------------------------------------------------------------
// Split-K GEMM writing fp32 partials at part + kz*M*N. STRIP: XCD swizzle.
// ---------------------------------------------------------------------------
template <int STRIP>
__global__ __launch_bounds__(256) void gemm_split(const __hip_bfloat16* __restrict__ A,
                                                  const __hip_bfloat16* __restrict__ Bt,
                                                  float* __restrict__ part,
                                                  int M, int N, int K, int Ksub) {
    __shared__ __align__(16) __hip_bfloat16 As[64 * 128];
    __shared__ __align__(16) __hip_bfloat16 Bs[64 * 128];
    const int tid = threadIdx.x;
    const int w = tid >> 6, lane = tid & 63;
    const int wm = (w >> 1) * 32, wn = (w & 1) * 32;
    const int quad = lane >> 4, l16 = lane & 15;
    int bid = blockIdx.x;
    int r = bid >> 3;
    int bx = (bid & 7) * STRIP + (r % STRIP);
    int by = r / STRIP;
    const int bm = by * 64, bn = bx * 64;
    const int kz = blockIdx.z;
    floatx4 acc[2][2];
#pragma unroll
    for (int i = 0; i < 2; ++i)
#pragma unroll
        for (int j = 0; j < 2; ++j) acc[i][j] = (floatx4)0.f;
    gemm_core(A, Bt, K, bm, bn, kz * Ksub, kz * Ksub + Ksub, As, Bs, acc);
#pragma unroll
    for (int mt = 0; mt < 2; ++mt)
#pragma unroll
        for (int nt = 0; nt < 2; ++nt)
#pragma unroll
            for (int rr = 0; rr < 4; ++rr) {
                int row = bm + wm + mt * 16 + quad * 4 + rr;
                int col = bn + wn + nt * 16 + l16;
                part[((size_t)kz * M + row) * N + col] = acc[mt][nt][rr];
            }
}

// ---------------------------------------------------------------------------
// Split-K=2 reduce for w1: h1 = bf16(relu(p0+p1+b1))
// ---------------------------------------------------------------------------
__global__ __launch_bounds__(256) void w1red(const float* __restrict__ part,
                                             const float* __restrict__ b1,
                                             __hip_bfloat16* __restrict__ h1) {
    size_t e = ((size_t)blockIdx.x * 256 + threadIdx.x) * 4;
    const size_t MN = (size_t)L_SEQ * F_DIM;
    float4 p0 = *(const float4*)(part + e);
    float4 p1 = *(const float4*)(part + MN + e);
    float4 bb = *(const float4*)(b1 + (e & (F_DIM - 1)));
    h1[e + 0] = (__hip_bfloat16)fmaxf(p0.x + p1.x + bb.x, 0.f);
    h1[e + 1] = (__hip_bfloat16)fmaxf(p0.y + p1.y + bb.y, 0.f);
    h1[e + 2] = (__hip_bfloat16)fmaxf(p0.z + p1.z + bb.z, 0.f);
    h1[e + 3] = (__hip_bfloat16)fmaxf(p0.w + p1.w + bb.w, 0.f);
}

// ---------------------------------------------------------------------------
// Split-K=4 reduce for w2: out = relu(sum partial + b2) + x
// ---------------------------------------------------------------------------
__global__ __launch_bounds__(256) void w2red(const float* __restrict__ part,
                                             const float* __restrict__ b2,
                                             const float* __restrict__ x,
                                             float* __restrict__ out) {
    size_t e = ((size_t)blockIdx.x * 256 + threadIdx.x) * 4;
    const size_t MN = (size_t)L_SEQ * D_DIM;
    float4 v0 = *(const float4*)(part + e);
    float4 v1 = *(const float4*)(part + MN + e);
    float4 v2 = *(const float4*)(part + 2 * MN + e);
    float4 v3 = *(const float4*)(part + 3 * MN + e);
    float4 bb = *(const float4*)(b2 + (e & 511));
    float4 xx = *(const float4*)(x + e);
    float4 r;
    r.x = fmaxf(v0.x + v1.x + v2.x + v3.x + bb.x, 0.f) + xx.x;
    r.y = fmaxf(v0.y + v1.y + v2.y + v3.y + bb.y, 0.f) + xx.y;
    r.z = fmaxf(v0.z + v1.z + v2.z + v3.z + bb.z, 0.f) + xx.z;
    r.w = fmaxf(v0.w + v1.w + v2.w + v3.w + bb.w, 0.f) + xx.w;
    *(float4*)(out + e) = r;
}

// ---------------------------------------------------------------------------
// Pass A (+ka fused): per-chunk KV sums; dg==0 blocks also write Ka.
// ---------------------------------------------------------------------------
__global__ __launch_bounds__(256) void passA_kernel(const float* __restrict__ qk,
                                                    const __hip_bfloat16* __restrict__ v,
                                                    float* __restrict__ S,
                                                    float* __restrict__ Ka) {
    int c = blockIdx.x, h = blockIdx.y, dg = blockIdx.z;
    int tid = threadIdx.x;
    int d = dg * 256 + tid;
    __shared__ float ks[CH][A_DIM];
    for (int e = tid; e < CH * A_DIM; e += 256) {
        int l = e >> 5, a = e & 31;
        ks[l][a] = qk[(c * CH + l) * QKN + 256 + a * H_DIM + h];
    }
    __syncthreads();
    float acc[A_DIM];
#pragma unroll
    for (int a = 0; a < A_DIM; ++a) acc[a] = 0.f;
    for (int l = 0; l < CH; ++l) {
        float vv = (float)v[(size_t)(c * CH + l) * DH + h * D_DIM + d];
#pragma unroll
        for (int a = 0; a < A_DIM; ++a) acc[a] += ks[l][a] * vv;
    }
#pragma unroll
    for (int a = 0; a < A_DIM; ++a)
        S[(size_t)((c * A_DIM + a) * H_DIM + h) * D_DIM + d] = acc[a];
    if (dg == 0 && tid < 32) {
        float s = 0.f;
        for (int l = 0; l < CH; ++l) s += ks[l][tid];
        Ka[c * AH + tid * H_DIM + h] = s;
    }
}

__global__ __launch_bounds__(256) void scanS_kernel(const float* __restrict__ S,
                                                    float* __restrict__ P) {
    int j = blockIdx.x * 256 + threadIdx.x;
    float run = 0.f;
    for (int c = 0; c < NC; ++c) {
        P[(size_t)c * (A_DIM * H_DIM * D_DIM) + j] = run;
        run += S[(size_t)c * (A_DIM * H_DIM * D_DIM) + j];
    }
}

// ---------------------------------------------------------------------------
// Pass C (+den fused): recurrence -> qkv bf16; dg==0 wave-0 computes den.
// ---------------------------------------------------------------------------
__global__ __launch_bounds__(256) void passC_kernel(const float* __restrict__ qk,
                                                    const __hip_bfloat16* __restrict__ v,
                                                    const float* __restrict__ P,
                                                    const float* __restrict__ Ka,
                                                    __hip_bfloat16* __restrict__ qkv,
                                                    float* __restrict__ den) {
    int c = blockIdx.x, h = blockIdx.y, dg = blockIdx.z;
    int tid = threadIdx.x;
    int d = dg * 256 + tid;
    __shared__ float ks[CH][A_DIM];
    __shared__ float qs[CH][A_DIM];
    for (int e = tid; e < CH * A_DIM; e += 256) {
        int l = e >> 5, a = e & 31;
        int gi = (c * CH + l) * QKN + a * H_DIM + h;
        qs[l][a] = qk[gi];
        ks[l][a] = qk[gi + 256];
    }
    __syncthreads();
    float st[A_DIM];
#pragma unroll
    for (int a = 0; a < A_DIM; ++a)
        st[a] = P[(size_t)((c * A_DIM + a) * H_DIM + h) * D_DIM + d];
    for (int l = 0; l < CH; ++l) {
        float vv = (float)v[(size_t)(c * CH + l) * DH + h * D_DIM + d];
        float s = 0.f;
#pragma unroll
        for (int a = 0; a < A_DIM; ++a) {
            st[a] += ks[l][a] * vv;
            s += qs[l][a] * st[a];
        }
        qkv[(size_t)(c * CH + l) * DH + h * D_DIM + d] = (__hip_bfloat16)s;
    }
    if (dg == 0 && tid < 32) {
        int a = tid;
        float kc = 0.f;
        for (int cc = 0; cc < c; ++cc) kc += Ka[cc * AH + a * H_DIM + h];
        for (int l = 0; l < CH; ++l) {
            kc += ks[l][a];
            float p = qs[l][a] * kc;
#pragma unroll
            for (int off = 16; off > 0; off >>= 1) p += __shfl_down(p, off, 32);
            if (a == 0) den[(c * CH + l) * H_DIM + h] = p;
        }
    }
}

// ---------------------------------------------------------------------------
// LN1 over (D,H) + residual. qkv bf16 [l][h*D+d]; y bf16 [l][d*H+h].
// ---------------------------------------------------------------------------
__global__ __launch_bounds__(256) void ln1_kernel(const __hip_bfloat16* __restrict__ qkv,
                                                  const float* __restrict__ den,
                                                  const float* __restrict__ x,
                                                  const float* __restrict__ w,
                                                  const float* __restrict__ b,
                                                  __hip_bfloat16* __restrict__ y) {
    int l = blockIdx.x, tid = threadIdx.x;
    __shared__ float dsh[8];
    __shared__ float yl[DH];
    __shared__ float red[8];
    if (tid < 8) dsh[tid] = den[l * H_DIM + tid];
    __syncthreads();
    float t[16];
    float s = 0.f, s2 = 0.f;
#pragma unroll
    for (int j = 0; j < 16; ++j) {
        int e = j * 256 + tid;
        float val = (float)qkv[(size_t)l * DH + e] / dsh[e >> 9];
        t[j] = val;
        s += val;
        s2 += val * val;
    }
    for (int off = 32; off > 0; off >>= 1) {
        s += __shfl_down(s, off);
        s2 += __shfl_down(s2, off);
    }
    int lane = tid & 63, wid = tid >> 6;
    if (lane == 0) { red[wid] = s; red[4 + wid] = s2; }
    __syncthreads();
    float ts = red[0] + red[1] + red[2] + red[3];
    float t2 = red[4] + red[5] + red[6] + red[7];
    float mu = ts / (float)DH;
    float var = t2 / (float)DH - mu * mu;
    float rs = rsqrtf(var + EPS_LN);
#pragma unroll
    for (int j = 0; j < 16; ++j) {
        int e = j * 256 + tid;
        int h = e >> 9, d = e & 511;
        int dh = d * H_DIM + h;
        yl[dh] = x[l * D_DIM + d] + (t[j] - mu) * rs * w[dh] + b[dh];
    }
    __syncthreads();
#pragma unroll
    for (int j = 0; j < 16; ++j) {
        int e = j * 256 + tid;
        y[(size_t)l * DH + e] = (__hip_bfloat16)yl[e];
    }
}

// ---------------------------------------------------------------------------
// Launch
// ---------------------------------------------------------------------------
extern "C" void kernel_launch(void* const* d_in, const int* in_sizes, int n_in,
                              void* d_out, int out_size, void* d_ws, size_t ws_size,
                              hipStream_t stream) {
    const float* x     = (const float*)d_in[0];
    const float* ln0_w = (const float*)d_in[1];
    const float* ln0_b = (const float*)d_in[2];
    const float* ln1_w = (const float*)d_in[3];
    const float* ln1_b = (const float*)d_in[4];
    const float* qw    = (const float*)d_in[5];
    const float* qb    = (const float*)d_in[6];
    const float* kw    = (const float*)d_in[7];
    const float* kb    = (const float*)d_in[8];
    const float* vw    = (const float*)d_in[9];
    const float* vb    = (const float*)d_in[10];
    const float* w1    = (const float*)d_in[11];
    const float* b1    = (const float*)d_in[12];
    const float* w2    = (const float*)d_in[13];
    const float* b2    = (const float*)d_in[14];
    float* out = (float*)d_out;

    char* ws = (char*)d_ws;
    __hip_bfloat16* xn_bf = (__hip_bfloat16*)(ws + 0);         // 1 MB
    __hip_bfloat16* xbf   = (__hip_bfloat16*)(ws + 1048576);   // 1 MB
    __hip_bfloat16* qkwt  = (__hip_bfloat16*)(ws + 2097152);   // 0.5 MB
    __hip_bfloat16* vwt   = (__hip_bfloat16*)(ws + 2621440);   // 4 MB
    __hip_bfloat16* w1t   = (__hip_bfloat16*)(ws + 6815744);   // 16 MB
    __hip_bfloat16* w2t   = (__hip_bfloat16*)(ws + 23592960);  // 2 MB
    float* qk  = (float*)(ws + 25690112);                      // 2 MB
    __hip_bfloat16* vb16 = (__hip_bfloat16*)(ws + 27787264);   // 8 MB
    float* S   = (float*)(ws + 36175872);                      // 8 MB
    float* P   = (float*)(ws + 44564480);                      // 8 MB
    __hip_bfloat16* qkvb = (__hip_bfloat16*)(ws + 52953088);   // 8 MB
    float* Ka  = (float*)(ws + 61341696);                      // 16 KB
    float* den = (float*)(ws + 61358080);                      // 32 KB
    float* w1part = (float*)(ws + 61440000);                   // 16 MB
    __hip_bfloat16* y  = (__hip_bfloat16*)P;     // alias: P dead after passC
    __hip_bfloat16* h1 = (__hip_bfloat16*)S;     // alias: S dead after scanS
    float* w2part = (float*)qkvb;                // alias: qkvb dead after ln1

    // fused LN0 + weight converts
    prep_kernel<<<12544, 256, 0, stream>>>(x, ln0_w, ln0_b, qw, kw, vw, w1, w2,
                                           xn_bf, xbf, qkwt, vwt, w1t, w2t);
    // fused q|k and v projections (one dispatch, 1152 blocks)
    qkv_gemm<<<1152, 256, 0, stream>>>(xn_bf, xbf, qkwt, vwt, qb, kb, vb, qk, vb16);
    // chunked KV scan (+ka, +den fused)
    passA_kernel<<<dim3(NC, H_DIM, 2), 256, 0, stream>>>(qk, vb16, S, Ka);
    scanS_kernel<<<(A_DIM * H_DIM * D_DIM) / 256, 256, 0, stream>>>(S, P);
    passC_kernel<<<dim3(NC, H_DIM, 2), 256, 0, stream>>>(qk, vb16, P, Ka, qkvb, den);
    // LN1 + residual -> y bf16
    ln1_kernel<<<L_SEQ, 256, 0, stream>>>(qkvb, den, x, ln1_w, ln1_b, y);
    // w1: split-K=2, strip=4
    gemm_split<4><<<dim3(512, 1, 2), 256, 0, stream>>>(y, w1t, w1part,
                                                       L_SEQ, F_DIM, DH, DH / 2);
    w1red<<<(L_SEQ * F_DIM) / 1024, 256, 0, stream>>>(w1part, b1, h1);
    // w2: split-K=4, strip=1
    gemm_split<1><<<dim3(128, 1, 4), 256, 0, stream>>>(h1, w2t, w2part,
                                                       L_SEQ, D_DIM, F_DIM, F_DIM / 4);
    w2red<<<(L_SEQ * D_DIM) / 1024, 256, 0, stream>>>(w2part, b2, x, out);

    (void)in_sizes; (void)n_in; (void)out_size; (void)ws_size;
}

// Round 6
// 229.758 us; speedup vs baseline: 1.1619x; 1.1619x over previous
//
#include <hip/hip_runtime.h>
#include <hip/hip_bf16.h>
#include <math.h>

#define L_SEQ 1024
#define D_DIM 512
#define A_DIM 32
#define H_DIM 8
#define F_DIM 2048
#define AH 256
#define DH 4096
#define NC 16
#define CH 64
#define QKN 512
#define EPS_LN 1e-5f

typedef __attribute__((ext_vector_type(8))) short short8;
typedef __attribute__((ext_vector_type(4))) float floatx4;

#define ASYNC_COPY16(gp, lp)                                                     \
    __builtin_amdgcn_global_load_lds(                                            \
        (const __attribute__((address_space(1))) void*)(const void*)(gp),        \
        (__attribute__((address_space(3))) void*)(void*)(lp), 16, 0, 0)

// ---------------------------------------------------------------------------
// prep: fused LN0 (+bf16 casts of x) and all weight transpose/converts.
// ---------------------------------------------------------------------------
__global__ __launch_bounds__(256) void prep_kernel(const float* __restrict__ x,
                                                   const float* __restrict__ ln0w,
                                                   const float* __restrict__ ln0b,
                                                   const float* __restrict__ qw,
                                                   const float* __restrict__ kw,
                                                   const float* __restrict__ vw,
                                                   const float* __restrict__ w1,
                                                   const float* __restrict__ w2,
                                                   __hip_bfloat16* __restrict__ xn,
                                                   __hip_bfloat16* __restrict__ xb,
                                                   __hip_bfloat16* __restrict__ qkwt,
                                                   __hip_bfloat16* __restrict__ vwt,
                                                   __hip_bfloat16* __restrict__ w1t,
                                                   __hip_bfloat16* __restrict__ w2t) {
    __shared__ float tt[32][33];
    __shared__ float red[8];
    int bid = blockIdx.x;
    int tid = threadIdx.x;
    if (bid < 1024) {
        int l = bid;
        float v0 = x[l * D_DIM + tid];
        float v1 = x[l * D_DIM + 256 + tid];
        float s = v0 + v1, s2 = v0 * v0 + v1 * v1;
        for (int off = 32; off > 0; off >>= 1) {
            s += __shfl_down(s, off);
            s2 += __shfl_down(s2, off);
        }
        int lane = tid & 63, wid = tid >> 6;
        if (lane == 0) { red[wid] = s; red[4 + wid] = s2; }
        __syncthreads();
        float ts = red[0] + red[1] + red[2] + red[3];
        float t2 = red[4] + red[5] + red[6] + red[7];
        float mu = ts / (float)D_DIM;
        float var = t2 / (float)D_DIM - mu * mu;
        float rs = rsqrtf(var + EPS_LN);
        xn[l * D_DIM + tid]       = (__hip_bfloat16)((v0 - mu) * rs * ln0w[tid] + ln0b[tid]);
        xn[l * D_DIM + 256 + tid] = (__hip_bfloat16)((v1 - mu) * rs * ln0w[256 + tid] + ln0b[256 + tid]);
        xb[l * D_DIM + tid]       = (__hip_bfloat16)v0;
        xb[l * D_DIM + 256 + tid] = (__hip_bfloat16)v1;
        return;
    }
    const float* in;
    __hip_bfloat16* out;
    int R, C, mode = 0, t;
    if (bid < 1152)      { t = bid - 1024;  in = qw; out = qkwt;                      R = 512;  C = 256; }
    else if (bid < 1280) { t = bid - 1152;  in = kw; out = qkwt + (size_t)AH * D_DIM; R = 512;  C = 256; }
    else if (bid < 3328) { t = bid - 1280;  in = vw; out = vwt;  mode = 1;            R = 512;  C = 4096; }
    else if (bid < 11520){ t = bid - 3328;  in = w1; out = w1t;                       R = 4096; C = 2048; }
    else                 { t = bid - 11520; in = w2; out = w2t;                       R = 2048; C = 512; }
    int ctiles = C >> 5;
    int cx = t % ctiles, cy = t / ctiles;
    int tx = tid & 31, ti = tid >> 5;
    int r0 = cy * 32, c0 = cx * 32;
#pragma unroll
    for (int ii = 0; ii < 4; ++ii)
        tt[ti + ii * 8][tx] = in[(size_t)(r0 + ti + ii * 8) * C + c0 + tx];
    __syncthreads();
#pragma unroll
    for (int ii = 0; ii < 4; ++ii) {
        int c = c0 + ti + ii * 8;
        int orow = mode ? (((c & 7) << 9) | (c >> 3)) : c;
        out[(size_t)orow * R + r0 + tx] = (__hip_bfloat16)tt[tx][ti + ii * 8];
    }
}

// ---------------------------------------------------------------------------
// Shared BK=128 MFMA core (for the big GEMMs).
// ---------------------------------------------------------------------------
__device__ __forceinline__ void gemm_core(const __hip_bfloat16* __restrict__ A,
                                          const __hip_bfloat16* __restrict__ Bt,
                                          int K, int bm, int bn, int k_beg, int k_end,
                                          __hip_bfloat16* As, __hip_bfloat16* Bs,
                                          floatx4 acc[2][2]) {
    const int tid = threadIdx.x;
    const int w = tid >> 6, lane = tid & 63;
    const int wm = (w >> 1) * 32, wn = (w & 1) * 32;
    const int quad = lane >> 4, l16 = lane & 15;
    const int srow = tid >> 4, sslot = tid & 15;
    const int scg = sslot ^ srow;
    for (int k0 = k_beg; k0 < k_end; k0 += 128) {
        __syncthreads();
#pragma unroll
        for (int j = 0; j < 4; ++j) {
            ASYNC_COPY16(A + (size_t)(bm + j * 16 + srow) * K + k0 + scg * 8,
                         As + j * 2048 + w * 512);
            ASYNC_COPY16(Bt + (size_t)(bn + j * 16 + srow) * K + k0 + scg * 8,
                         Bs + j * 2048 + w * 512);
        }
        __syncthreads();
#pragma unroll
        for (int ks = 0; ks < 4; ++ks) {
            short8 af[2], bfr[2];
#pragma unroll
            for (int mt = 0; mt < 2; ++mt) {
                int rr = wm + mt * 16 + l16;
                af[mt] = *(const short8*)(As + rr * 128 + (((ks * 4 + quad) ^ (rr & 15)) * 8));
            }
#pragma unroll
            for (int nt = 0; nt < 2; ++nt) {
                int rr = wn + nt * 16 + l16;
                bfr[nt] = *(const short8*)(Bs + rr * 128 + (((ks * 4 + quad) ^ (rr & 15)) * 8));
            }
#pragma unroll
            for (int mt = 0; mt < 2; ++mt)
#pragma unroll
                for (int nt = 0; nt < 2; ++nt)
                    acc[mt][nt] = __builtin_amdgcn_mfma_f32_16x16x32_bf16(
                        af[mt], bfr[nt], acc[mt][nt], 0, 0, 0);
        }
    }
}

// ---------------------------------------------------------------------------
// Fused q|k and v projections in one dispatch.
// ---------------------------------------------------------------------------
__global__ __launch_bounds__(256) void qkv_gemm(const __hip_bfloat16* __restrict__ xn,
                                                const __hip_bfloat16* __restrict__ xb,
                                                const __hip_bfloat16* __restrict__ qkwt,
                                                const __hip_bfloat16* __restrict__ vwt,
                                                const float* __restrict__ qb,
                                                const float* __restrict__ kb,
                                                const float* __restrict__ vb,
                                                float* __restrict__ qk,
                                                __hip_bfloat16* __restrict__ v) {
    __shared__ __align__(16) __hip_bfloat16 As[64 * 128];
    __shared__ __align__(16) __hip_bfloat16 Bs[64 * 128];
    const int tid = threadIdx.x;
    const int w = tid >> 6, lane = tid & 63;
    const int wm = (w >> 1) * 32, wn = (w & 1) * 32;
    const int quad = lane >> 4, l16 = lane & 15;
    int bid = blockIdx.x;
    bool isv = bid < 1024;
    const __hip_bfloat16 *A, *Bt;
    int bx, by;
    if (isv) {
        int r = bid >> 3;
        bx = (bid & 7) * 8 + (r & 7);
        by = r >> 3;
        A = xb; Bt = vwt;
    } else {
        int b2 = bid - 1024;
        bx = b2 & 7; by = b2 >> 3;
        A = xn; Bt = qkwt;
    }
    const int bm = by * 64, bn = bx * 64;
    floatx4 acc[2][2];
#pragma unroll
    for (int i = 0; i < 2; ++i)
#pragma unroll
        for (int j = 0; j < 2; ++j) acc[i][j] = (floatx4)0.f;
    gemm_core(A, Bt, D_DIM, bm, bn, 0, D_DIM, As, Bs, acc);
#pragma unroll
    for (int mt = 0; mt < 2; ++mt)
#pragma unroll
        for (int nt = 0; nt < 2; ++nt)
#pragma unroll
            for (int r = 0; r < 4; ++r) {
                int row = bm + wm + mt * 16 + quad * 4 + r;
                int col = bn + wn + nt * 16 + l16;
                float val = acc[mt][nt][r];
                if (isv) {
                    int bi = ((col & 511) << 3) | (col >> 9);
                    v[(size_t)row * DH + col] = (__hip_bfloat16)(val + vb[bi]);
                } else {
                    float bb = (col < 256) ? qb[col] : kb[col - 256];
                    qk[(size_t)row * QKN + col] = expf(fminf(fmaxf(val + bb, -10.f), 10.f));
                }
            }
}

// ---------------------------------------------------------------------------
// Split-K GEMM writing fp32 partials. STRIP: XCD swizzle.
// ---------------------------------------------------------------------------
template <int STRIP>
__global__ __launch_bounds__(256) void gemm_split(const __hip_bfloat16* __restrict__ A,
                                                  const __hip_bfloat16* __restrict__ Bt,
                                                  float* __restrict__ part,
                                                  int M, int N, int K, int Ksub) {
    __shared__ __align__(16) __hip_bfloat16 As[64 * 128];
    __shared__ __align__(16) __hip_bfloat16 Bs[64 * 128];
    const int tid = threadIdx.x;
    const int w = tid >> 6, lane = tid & 63;
    const int wm = (w >> 1) * 32, wn = (w & 1) * 32;
    const int quad = lane >> 4, l16 = lane & 15;
    int bid = blockIdx.x;
    int r = bid >> 3;
    int bx = (bid & 7) * STRIP + (r % STRIP);
    int by = r / STRIP;
    const int bm = by * 64, bn = bx * 64;
    const int kz = blockIdx.z;
    floatx4 acc[2][2];
#pragma unroll
    for (int i = 0; i < 2; ++i)
#pragma unroll
        for (int j = 0; j < 2; ++j) acc[i][j] = (floatx4)0.f;
    gemm_core(A, Bt, K, bm, bn, kz * Ksub, kz * Ksub + Ksub, As, Bs, acc);
#pragma unroll
    for (int mt = 0; mt < 2; ++mt)
#pragma unroll
        for (int nt = 0; nt < 2; ++nt)
#pragma unroll
            for (int rr = 0; rr < 4; ++rr) {
                int row = bm + wm + mt * 16 + quad * 4 + rr;
                int col = bn + wn + nt * 16 + l16;
                part[((size_t)kz * M + row) * N + col] = acc[mt][nt][rr];
            }
}

__global__ __launch_bounds__(256) void w1red(const float* __restrict__ part,
                                             const float* __restrict__ b1,
                                             __hip_bfloat16* __restrict__ h1) {
    size_t e = ((size_t)blockIdx.x * 256 + threadIdx.x) * 4;
    const size_t MN = (size_t)L_SEQ * F_DIM;
    float4 p0 = *(const float4*)(part + e);
    float4 p1 = *(const float4*)(part + MN + e);
    float4 bb = *(const float4*)(b1 + (e & (F_DIM - 1)));
    h1[e + 0] = (__hip_bfloat16)fmaxf(p0.x + p1.x + bb.x, 0.f);
    h1[e + 1] = (__hip_bfloat16)fmaxf(p0.y + p1.y + bb.y, 0.f);
    h1[e + 2] = (__hip_bfloat16)fmaxf(p0.z + p1.z + bb.z, 0.f);
    h1[e + 3] = (__hip_bfloat16)fmaxf(p0.w + p1.w + bb.w, 0.f);
}

__global__ __launch_bounds__(256) void w2red(const float* __restrict__ part,
                                             const float* __restrict__ b2,
                                             const float* __restrict__ x,
                                             float* __restrict__ out) {
    size_t e = ((size_t)blockIdx.x * 256 + threadIdx.x) * 4;
    const size_t MN = (size_t)L_SEQ * D_DIM;
    float4 v0 = *(const float4*)(part + e);
    float4 v1 = *(const float4*)(part + MN + e);
    float4 v2 = *(const float4*)(part + 2 * MN + e);
    float4 v3 = *(const float4*)(part + 3 * MN + e);
    float4 bb = *(const float4*)(b2 + (e & 511));
    float4 xx = *(const float4*)(x + e);
    float4 r;
    r.x = fmaxf(v0.x + v1.x + v2.x + v3.x + bb.x, 0.f) + xx.x;
    r.y = fmaxf(v0.y + v1.y + v2.y + v3.y + bb.y, 0.f) + xx.y;
    r.z = fmaxf(v0.z + v1.z + v2.z + v3.z + bb.z, 0.f) + xx.z;
    r.w = fmaxf(v0.w + v1.w + v2.w + v3.w + bb.w, 0.f) + xx.w;
    *(float4*)(out + e) = r;
}

// ---------------------------------------------------------------------------
// Kernel A (MFMA): S_c[a][d] = sum_l k[c,l,a]*v[c,l,d] per h, d-quarter.
// Also Ka chunk sums (dq==0). grid (NC, H, 4).
// ---------------------------------------------------------------------------
__global__ __launch_bounds__(256) void kvchunk_kernel(const float* __restrict__ qk,
                                                      const __hip_bfloat16* __restrict__ v,
                                                      float* __restrict__ S,
                                                      float* __restrict__ Ka) {
    int c = blockIdx.x, h = blockIdx.y, dq = blockIdx.z;
    int tid = threadIdx.x;
    __shared__ __align__(16) __hip_bfloat16 kaT[32][72];  // [a][l]
    __shared__ __align__(16) __hip_bfloat16 Vl[128][72];  // [d][l]
    for (int e = tid; e < 2048; e += 256) {
        int l = e >> 5, a = e & 31;
        kaT[a][l] = (__hip_bfloat16)qk[(c * CH + l) * QKN + 256 + a * 8 + h];
    }
#pragma unroll
    for (int it = 0; it < 4; ++it) {
        int r = tid + it * 256;
        int l = r >> 4, dg8 = (r & 15) * 8;
        short8 vv = *(const short8*)(v + (size_t)(c * CH + l) * DH + h * D_DIM + dq * 128 + dg8);
#pragma unroll
        for (int j = 0; j < 8; ++j)
            Vl[dg8 + j][l] = ((const __hip_bfloat16*)&vv)[j];
    }
    __syncthreads();
    int w = tid >> 6, lane = tid & 63, quad = lane >> 4, l16 = lane & 15;
    floatx4 acc[2][2];
#pragma unroll
    for (int i = 0; i < 2; ++i)
#pragma unroll
        for (int j = 0; j < 2; ++j) acc[i][j] = (floatx4)0.f;
#pragma unroll
    for (int ks = 0; ks < 2; ++ks) {
        short8 af[2], bfr[2];
#pragma unroll
        for (int mt = 0; mt < 2; ++mt)
            af[mt] = *(const short8*)&kaT[mt * 16 + l16][ks * 32 + quad * 8];
#pragma unroll
        for (int nt = 0; nt < 2; ++nt)
            bfr[nt] = *(const short8*)&Vl[w * 32 + nt * 16 + l16][ks * 32 + quad * 8];
#pragma unroll
        for (int mt = 0; mt < 2; ++mt)
#pragma unroll
            for (int nt = 0; nt < 2; ++nt)
                acc[mt][nt] = __builtin_amdgcn_mfma_f32_16x16x32_bf16(
                    af[mt], bfr[nt], acc[mt][nt], 0, 0, 0);
    }
#pragma unroll
    for (int mt = 0; mt < 2; ++mt)
#pragma unroll
        for (int nt = 0; nt < 2; ++nt)
#pragma unroll
            for (int r = 0; r < 4; ++r) {
                int a = mt * 16 + quad * 4 + r;
                int d = dq * 128 + w * 32 + nt * 16 + l16;
                S[(size_t)((c * A_DIM + a) * H_DIM + h) * D_DIM + d] = acc[mt][nt][r];
            }
    if (dq == 0 && tid < 32) {
        float s = 0.f;
        for (int l = 0; l < CH; ++l) s += (float)kaT[tid][l];
        Ka[c * AH + tid * 8 + h] = s;
    }
}

// ---------------------------------------------------------------------------
// Scan: exclusive chunk prefix. P2 bf16 in [c][h][d][a] layout (B-operand);
// KaP exclusive prefix of Ka. grid (16 dt, 8 h).
// ---------------------------------------------------------------------------
__global__ __launch_bounds__(256) void scan_kernel(const float* __restrict__ S,
                                                   const float* __restrict__ Ka,
                                                   __hip_bfloat16* __restrict__ P2,
                                                   float* __restrict__ KaP) {
    int dt = blockIdx.x, h = blockIdx.y;
    int tid = threadIdx.x;
    __shared__ float t[32][33];
    int dloc = tid & 31, arow = tid >> 5;
    float run[4] = {0.f, 0.f, 0.f, 0.f};
    int dw = tid >> 3, a4 = (tid & 7) * 4;
    for (int c = 0; c < NC; ++c) {
#pragma unroll
        for (int i = 0; i < 4; ++i) t[arow + 8 * i][dloc] = run[i];
        __syncthreads();
        __hip_bfloat16 o[4];
#pragma unroll
        for (int j = 0; j < 4; ++j) o[j] = (__hip_bfloat16)t[a4 + j][dw];
        *(float2*)&P2[((size_t)((c * 8 + h) * 512 + dt * 32 + dw)) * 32 + a4] = *(float2*)o;
#pragma unroll
        for (int i = 0; i < 4; ++i)
            run[i] += S[(size_t)((c * A_DIM + arow + 8 * i) * H_DIM + h) * D_DIM + dt * 32 + dloc];
        __syncthreads();
    }
    if (dt == 0 && tid < 32) {
        float rk = 0.f;
        for (int c = 0; c < NC; ++c) {
            KaP[c * AH + tid * 8 + h] = rk;
            rk += Ka[c * AH + tid * 8 + h];
        }
    }
}

// ---------------------------------------------------------------------------
// Kernel C (MFMA): qkv = mask(Q K^T) V + Q P ; den = rowsum(mask(QK^T)) + q.KaP
// grid (NC, H, 4 dq).
// ---------------------------------------------------------------------------
__global__ __launch_bounds__(256) void passC_kernel(const float* __restrict__ qk,
                                                    const __hip_bfloat16* __restrict__ v,
                                                    const __hip_bfloat16* __restrict__ P2,
                                                    const float* __restrict__ KaP,
                                                    __hip_bfloat16* __restrict__ qkv,
                                                    float* __restrict__ den) {
    int c = blockIdx.x, h = blockIdx.y, dq = blockIdx.z;
    int tid = threadIdx.x;
    __shared__ __align__(16) __hip_bfloat16 qa[64][40];   // [l][a]
    __shared__ __align__(16) __hip_bfloat16 ka[64][40];   // [l'][a]
    __shared__ __align__(16) __hip_bfloat16 Vl[128][72];  // [d][l']
    __shared__ __align__(16) __hip_bfloat16 Sc[64][72];   // [l][l']
    __shared__ float KaPs[32];
    for (int e = tid; e < 2048; e += 256) {
        int l = e >> 5, a = e & 31;
        int gi = (c * CH + l) * QKN + a * 8 + h;
        qa[l][a] = (__hip_bfloat16)qk[gi];
        ka[l][a] = (__hip_bfloat16)qk[gi + 256];
    }
#pragma unroll
    for (int it = 0; it < 4; ++it) {
        int r = tid + it * 256;
        int l = r >> 4, dg8 = (r & 15) * 8;
        short8 vv = *(const short8*)(v + (size_t)(c * CH + l) * DH + h * D_DIM + dq * 128 + dg8);
#pragma unroll
        for (int j = 0; j < 8; ++j)
            Vl[dg8 + j][l] = ((const __hip_bfloat16*)&vv)[j];
    }
    if (dq == 0 && tid < 32) KaPs[tid] = KaP[c * AH + tid * 8 + h];
    __syncthreads();
    int w = tid >> 6, lane = tid & 63, quad = lane >> 4, l16 = lane & 15;
    // Phase 1: QK^T for this wave's 16-row strip
    short8 afq = *(const short8*)&qa[w * 16 + l16][quad * 8];
    floatx4 sacc[4];
#pragma unroll
    for (int nt = 0; nt < 4; ++nt) sacc[nt] = (floatx4)0.f;
#pragma unroll
    for (int nt = 0; nt < 4; ++nt) {
        short8 bfr = *(const short8*)&ka[nt * 16 + l16][quad * 8];
        sacc[nt] = __builtin_amdgcn_mfma_f32_16x16x32_bf16(afq, bfr, sacc[nt], 0, 0, 0);
    }
#pragma unroll
    for (int nt = 0; nt < 4; ++nt)
#pragma unroll
        for (int r = 0; r < 4; ++r) {
            int l = w * 16 + quad * 4 + r;
            int lp = nt * 16 + l16;
            Sc[l][lp] = (__hip_bfloat16)((lp <= l) ? sacc[nt][r] : 0.f);
        }
    __syncthreads();
    // Phase 2: den (dq==0, wave 0)
    if (dq == 0 && tid < 64) {
        int l = tid;
        float s = 0.f;
        for (int lp = 0; lp <= l; ++lp) s += (float)Sc[l][lp];
        for (int a = 0; a < A_DIM; ++a) s += (float)qa[l][a] * KaPs[a];
        den[(c * CH + l) * H_DIM + h] = s;
    }
    // Phase 3: qkv = Sc @ V + Q @ P
    floatx4 acc[8];
#pragma unroll
    for (int nt = 0; nt < 8; ++nt) acc[nt] = (floatx4)0.f;
#pragma unroll
    for (int nt = 0; nt < 8; ++nt) {
        short8 pb = *(const short8*)(P2 + ((size_t)((c * 8 + h) * 512 + dq * 128 + nt * 16 + l16)) * 32 + quad * 8);
        acc[nt] = __builtin_amdgcn_mfma_f32_16x16x32_bf16(afq, pb, acc[nt], 0, 0, 0);
    }
#pragma unroll
    for (int ks = 0; ks < 2; ++ks) {
        short8 afs = *(const short8*)&Sc[w * 16 + l16][ks * 32 + quad * 8];
#pragma unroll
        for (int nt = 0; nt < 8; ++nt) {
            short8 bfr = *(const short8*)&Vl[nt * 16 + l16][ks * 32 + quad * 8];
            acc[nt] = __builtin_amdgcn_mfma_f32_16x16x32_bf16(afs, bfr, acc[nt], 0, 0, 0);
        }
    }
#pragma unroll
    for (int nt = 0; nt < 8; ++nt)
#pragma unroll
        for (int r = 0; r < 4; ++r) {
            int l = w * 16 + quad * 4 + r;
            int d = dq * 128 + nt * 16 + l16;
            qkv[(size_t)(c * CH + l) * DH + h * D_DIM + d] = (__hip_bfloat16)acc[nt][r];
        }
}

// ---------------------------------------------------------------------------
// LN1 over (D,H) + residual. qkv bf16 [l][h*D+d]; y bf16 [l][d*H+h].
// ---------------------------------------------------------------------------
__global__ __launch_bounds__(256) void ln1_kernel(const __hip_bfloat16* __restrict__ qkv,
                                                  const float* __restrict__ den,
                                                  const float* __restrict__ x,
                                                  const float* __restrict__ w,
                                                  const float* __restrict__ b,
                                                  __hip_bfloat16* __restrict__ y) {
    int l = blockIdx.x, tid = threadIdx.x;
    __shared__ float dsh[8];
    __shared__ float yl[DH];
    __shared__ float red[8];
    if (tid < 8) dsh[tid] = den[l * H_DIM + tid];
    __syncthreads();
    float t[16];
    float s = 0.f, s2 = 0.f;
#pragma unroll
    for (int j = 0; j < 16; ++j) {
        int e = j * 256 + tid;
        float val = (float)qkv[(size_t)l * DH + e] / dsh[e >> 9];
        t[j] = val;
        s += val;
        s2 += val * val;
    }
    for (int off = 32; off > 0; off >>= 1) {
        s += __shfl_down(s, off);
        s2 += __shfl_down(s2, off);
    }
    int lane = tid & 63, wid = tid >> 6;
    if (lane == 0) { red[wid] = s; red[4 + wid] = s2; }
    __syncthreads();
    float ts = red[0] + red[1] + red[2] + red[3];
    float t2 = red[4] + red[5] + red[6] + red[7];
    float mu = ts / (float)DH;
    float var = t2 / (float)DH - mu * mu;
    float rs = rsqrtf(var + EPS_LN);
#pragma unroll
    for (int j = 0; j < 16; ++j) {
        int e = j * 256 + tid;
        int h = e >> 9, d = e & 511;
        int dh = d * H_DIM + h;
        yl[dh] = x[l * D_DIM + d] + (t[j] - mu) * rs * w[dh] + b[dh];
    }
    __syncthreads();
#pragma unroll
    for (int j = 0; j < 16; ++j) {
        int e = j * 256 + tid;
        y[(size_t)l * DH + e] = (__hip_bfloat16)yl[e];
    }
}

// ---------------------------------------------------------------------------
// Launch
// ---------------------------------------------------------------------------
extern "C" void kernel_launch(void* const* d_in, const int* in_sizes, int n_in,
                              void* d_out, int out_size, void* d_ws, size_t ws_size,
                              hipStream_t stream) {
    const float* x     = (const float*)d_in[0];
    const float* ln0_w = (const float*)d_in[1];
    const float* ln0_b = (const float*)d_in[2];
    const float* ln1_w = (const float*)d_in[3];
    const float* ln1_b = (const float*)d_in[4];
    const float* qw    = (const float*)d_in[5];
    const float* qb    = (const float*)d_in[6];
    const float* kw    = (const float*)d_in[7];
    const float* kb    = (const float*)d_in[8];
    const float* vw    = (const float*)d_in[9];
    const float* vb    = (const float*)d_in[10];
    const float* w1    = (const float*)d_in[11];
    const float* b1    = (const float*)d_in[12];
    const float* w2    = (const float*)d_in[13];
    const float* b2    = (const float*)d_in[14];
    float* out = (float*)d_out;

    char* ws = (char*)d_ws;
    __hip_bfloat16* xn_bf = (__hip_bfloat16*)(ws + 0);         // 1 MB
    __hip_bfloat16* xbf   = (__hip_bfloat16*)(ws + 1048576);   // 1 MB
    __hip_bfloat16* qkwt  = (__hip_bfloat16*)(ws + 2097152);   // 0.5 MB
    __hip_bfloat16* vwt   = (__hip_bfloat16*)(ws + 2621440);   // 4 MB
    __hip_bfloat16* w1t   = (__hip_bfloat16*)(ws + 6815744);   // 16 MB
    __hip_bfloat16* w2t   = (__hip_bfloat16*)(ws + 23592960);  // 2 MB
    float* qk  = (float*)(ws + 25690112);                      // 2 MB
    __hip_bfloat16* vb16 = (__hip_bfloat16*)(ws + 27787264);   // 8 MB
    float* S   = (float*)(ws + 36175872);                      // 8 MB
    __hip_bfloat16* P2 = (__hip_bfloat16*)(ws + 44564480);     // 4 MB
    __hip_bfloat16* qkvb = (__hip_bfloat16*)(ws + 52953088);   // 8 MB
    float* Ka  = (float*)(ws + 61341696);                      // 16 KB
    float* den = (float*)(ws + 61358080);                      // 32 KB
    float* KaP = (float*)(ws + 61390848);                      // 16 KB
    float* w1part = (float*)(ws + 61440000);                   // 16 MB
    __hip_bfloat16* y  = (__hip_bfloat16*)(ws + 44564480);  // alias: P2 dead after passC
    __hip_bfloat16* h1 = (__hip_bfloat16*)S;                // alias: S dead after scan
    float* w2part = (float*)qkvb;                           // alias: qkvb dead after ln1

    prep_kernel<<<12544, 256, 0, stream>>>(x, ln0_w, ln0_b, qw, kw, vw, w1, w2,
                                           xn_bf, xbf, qkwt, vwt, w1t, w2t);
    qkv_gemm<<<1152, 256, 0, stream>>>(xn_bf, xbf, qkwt, vwt, qb, kb, vb, qk, vb16);
    // MFMA chunked scan
    kvchunk_kernel<<<dim3(NC, H_DIM, 4), 256, 0, stream>>>(qk, vb16, S, Ka);
    scan_kernel<<<dim3(16, 8), 256, 0, stream>>>(S, Ka, P2, KaP);
    passC_kernel<<<dim3(NC, H_DIM, 4), 256, 0, stream>>>(qk, vb16, P2, KaP, qkvb, den);
    // LN1 + residual -> y bf16
    ln1_kernel<<<L_SEQ, 256, 0, stream>>>(qkvb, den, x, ln1_w, ln1_b, y);
    // MLP
    gemm_split<4><<<dim3(512, 1, 2), 256, 0, stream>>>(y, w1t, w1part,
                                                       L_SEQ, F_DIM, DH, DH / 2);
    w1red<<<(L_SEQ * F_DIM) / 1024, 256, 0, stream>>>(w1part, b1, h1);
    gemm_split<1><<<dim3(128, 1, 4), 256, 0, stream>>>(h1, w2t, w2part,
                                                       L_SEQ, D_DIM, F_DIM, F_DIM / 4);
    w2red<<<(L_SEQ * D_DIM) / 1024, 256, 0, stream>>>(w2part, b2, x, out);

    (void)in_sizes; (void)n_in; (void)out_size; (void)ws_size;
}

// Round 7
// 213.291 us; speedup vs baseline: 1.2516x; 1.0772x over previous
//
#include <hip/hip_runtime.h>
#include <hip/hip_bf16.h>
#include <math.h>

#define L_SEQ 1024
#define D_DIM 512
#define A_DIM 32
#define H_DIM 8
#define F_DIM 2048
#define AH 256
#define DH 4096
#define NC 16
#define CH 64
#define QKN 512
#define EPS_LN 1e-5f

typedef __attribute__((ext_vector_type(8))) short short8;
typedef __attribute__((ext_vector_type(4))) short short4v;
typedef __attribute__((ext_vector_type(4))) float floatx4;

#define ASYNC_COPY16(gp, lp)                                                     \
    __builtin_amdgcn_global_load_lds(                                            \
        (const __attribute__((address_space(1))) void*)(const void*)(gp),        \
        (__attribute__((address_space(3))) void*)(void*)(lp), 16, 0, 0)

// ---------------------------------------------------------------------------
// prep: fused LN0 (+bf16 casts of x) and all weight transpose/converts.
// ---------------------------------------------------------------------------
__global__ __launch_bounds__(256) void prep_kernel(const float* __restrict__ x,
                                                   const float* __restrict__ ln0w,
                                                   const float* __restrict__ ln0b,
                                                   const float* __restrict__ qw,
                                                   const float* __restrict__ kw,
                                                   const float* __restrict__ vw,
                                                   const float* __restrict__ w1,
                                                   const float* __restrict__ w2,
                                                   __hip_bfloat16* __restrict__ xn,
                                                   __hip_bfloat16* __restrict__ xb,
                                                   __hip_bfloat16* __restrict__ qkwt,
                                                   __hip_bfloat16* __restrict__ vwt,
                                                   __hip_bfloat16* __restrict__ w1t,
                                                   __hip_bfloat16* __restrict__ w2t) {
    __shared__ float tt[32][33];
    __shared__ float red[8];
    int bid = blockIdx.x;
    int tid = threadIdx.x;
    if (bid < 1024) {
        int l = bid;
        float v0 = x[l * D_DIM + tid];
        float v1 = x[l * D_DIM + 256 + tid];
        float s = v0 + v1, s2 = v0 * v0 + v1 * v1;
        for (int off = 32; off > 0; off >>= 1) {
            s += __shfl_down(s, off);
            s2 += __shfl_down(s2, off);
        }
        int lane = tid & 63, wid = tid >> 6;
        if (lane == 0) { red[wid] = s; red[4 + wid] = s2; }
        __syncthreads();
        float ts = red[0] + red[1] + red[2] + red[3];
        float t2 = red[4] + red[5] + red[6] + red[7];
        float mu = ts / (float)D_DIM;
        float var = t2 / (float)D_DIM - mu * mu;
        float rs = rsqrtf(var + EPS_LN);
        xn[l * D_DIM + tid]       = (__hip_bfloat16)((v0 - mu) * rs * ln0w[tid] + ln0b[tid]);
        xn[l * D_DIM + 256 + tid] = (__hip_bfloat16)((v1 - mu) * rs * ln0w[256 + tid] + ln0b[256 + tid]);
        xb[l * D_DIM + tid]       = (__hip_bfloat16)v0;
        xb[l * D_DIM + 256 + tid] = (__hip_bfloat16)v1;
        return;
    }
    const float* in;
    __hip_bfloat16* out;
    int R, C, mode = 0, t;
    if (bid < 1152)      { t = bid - 1024;  in = qw; out = qkwt;                      R = 512;  C = 256; }
    else if (bid < 1280) { t = bid - 1152;  in = kw; out = qkwt + (size_t)AH * D_DIM; R = 512;  C = 256; }
    else if (bid < 3328) { t = bid - 1280;  in = vw; out = vwt;  mode = 1;            R = 512;  C = 4096; }
    else if (bid < 11520){ t = bid - 3328;  in = w1; out = w1t;                       R = 4096; C = 2048; }
    else                 { t = bid - 11520; in = w2; out = w2t;                       R = 2048; C = 512; }
    int ctiles = C >> 5;
    int cx = t % ctiles, cy = t / ctiles;
    int tx = tid & 31, ti = tid >> 5;
    int r0 = cy * 32, c0 = cx * 32;
#pragma unroll
    for (int ii = 0; ii < 4; ++ii)
        tt[ti + ii * 8][tx] = in[(size_t)(r0 + ti + ii * 8) * C + c0 + tx];
    __syncthreads();
#pragma unroll
    for (int ii = 0; ii < 4; ++ii) {
        int c = c0 + ti + ii * 8;
        int orow = mode ? (((c & 7) << 9) | (c >> 3)) : c;
        out[(size_t)orow * R + r0 + tx] = (__hip_bfloat16)tt[tx][ti + ii * 8];
    }
}

// ---------------------------------------------------------------------------
// Shared BK=128 MFMA core.
// ---------------------------------------------------------------------------
__device__ __forceinline__ void gemm_core(const __hip_bfloat16* __restrict__ A,
                                          const __hip_bfloat16* __restrict__ Bt,
                                          int K, int bm, int bn, int k_beg, int k_end,
                                          __hip_bfloat16* As, __hip_bfloat16* Bs,
                                          floatx4 acc[2][2]) {
    const int tid = threadIdx.x;
    const int w = tid >> 6, lane = tid & 63;
    const int wm = (w >> 1) * 32, wn = (w & 1) * 32;
    const int quad = lane >> 4, l16 = lane & 15;
    const int srow = tid >> 4, sslot = tid & 15;
    const int scg = sslot ^ srow;
    for (int k0 = k_beg; k0 < k_end; k0 += 128) {
        __syncthreads();
#pragma unroll
        for (int j = 0; j < 4; ++j) {
            ASYNC_COPY16(A + (size_t)(bm + j * 16 + srow) * K + k0 + scg * 8,
                         As + j * 2048 + w * 512);
            ASYNC_COPY16(Bt + (size_t)(bn + j * 16 + srow) * K + k0 + scg * 8,
                         Bs + j * 2048 + w * 512);
        }
        __syncthreads();
#pragma unroll
        for (int ks = 0; ks < 4; ++ks) {
            short8 af[2], bfr[2];
#pragma unroll
            for (int mt = 0; mt < 2; ++mt) {
                int rr = wm + mt * 16 + l16;
                af[mt] = *(const short8*)(As + rr * 128 + (((ks * 4 + quad) ^ (rr & 15)) * 8));
            }
#pragma unroll
            for (int nt = 0; nt < 2; ++nt) {
                int rr = wn + nt * 16 + l16;
                bfr[nt] = *(const short8*)(Bs + rr * 128 + (((ks * 4 + quad) ^ (rr & 15)) * 8));
            }
#pragma unroll
            for (int mt = 0; mt < 2; ++mt)
#pragma unroll
                for (int nt = 0; nt < 2; ++nt)
                    acc[mt][nt] = __builtin_amdgcn_mfma_f32_16x16x32_bf16(
                        af[mt], bfr[nt], acc[mt][nt], 0, 0, 0);
        }
    }
}

// ---------------------------------------------------------------------------
// Fused q|k and v projections. v written TRANSPOSED: vT[h*512+d][l] (bf16).
// ---------------------------------------------------------------------------
__global__ __launch_bounds__(256) void qkv_gemm(const __hip_bfloat16* __restrict__ xn,
                                                const __hip_bfloat16* __restrict__ xb,
                                                const __hip_bfloat16* __restrict__ qkwt,
                                                const __hip_bfloat16* __restrict__ vwt,
                                                const float* __restrict__ qb,
                                                const float* __restrict__ kb,
                                                const float* __restrict__ vb,
                                                float* __restrict__ qk,
                                                __hip_bfloat16* __restrict__ vT) {
    __shared__ __align__(16) __hip_bfloat16 As[64 * 128];
    __shared__ __align__(16) __hip_bfloat16 Bs[64 * 128];
    const int tid = threadIdx.x;
    const int w = tid >> 6, lane = tid & 63;
    const int wm = (w >> 1) * 32, wn = (w & 1) * 32;
    const int quad = lane >> 4, l16 = lane & 15;
    int bid = blockIdx.x;
    bool isv = bid < 1024;
    const __hip_bfloat16 *A, *Bt;
    int bx, by;
    if (isv) {
        int r = bid >> 3;
        bx = (bid & 7) * 8 + (r & 7);
        by = r >> 3;
        A = xb; Bt = vwt;
    } else {
        int b2 = bid - 1024;
        bx = b2 & 7; by = b2 >> 3;
        A = xn; Bt = qkwt;
    }
    const int bm = by * 64, bn = bx * 64;
    floatx4 acc[2][2];
#pragma unroll
    for (int i = 0; i < 2; ++i)
#pragma unroll
        for (int j = 0; j < 2; ++j) acc[i][j] = (floatx4)0.f;
    gemm_core(A, Bt, D_DIM, bm, bn, 0, D_DIM, As, Bs, acc);
    if (isv) {
        // LDS-bounce transpose: Ct[col 64][row 72pad] then coalesced vT write
        __syncthreads();
        __hip_bfloat16* Ct = As;  // reuse (16 KB > 9.2 KB)
#pragma unroll
        for (int mt = 0; mt < 2; ++mt)
#pragma unroll
            for (int nt = 0; nt < 2; ++nt) {
                int col = bn + wn + nt * 16 + l16;
                int bi = ((col & 511) << 3) | (col >> 9);
                float bbv = vb[bi];
                __hip_bfloat16 tmp[4];
#pragma unroll
                for (int r = 0; r < 4; ++r)
                    tmp[r] = (__hip_bfloat16)(acc[mt][nt][r] + bbv);
                *(short4v*)&Ct[(wn + nt * 16 + l16) * 72 + wm + mt * 16 + quad * 4] =
                    *(short4v*)tmp;
            }
        __syncthreads();
        int colloc = tid >> 2, seg = (tid & 3) * 16;
        short8 o0 = *(const short8*)&Ct[colloc * 72 + seg];
        short8 o1 = *(const short8*)&Ct[colloc * 72 + seg + 8];
        *(short8*)(vT + (size_t)(bn + colloc) * 1024 + bm + seg) = o0;
        *(short8*)(vT + (size_t)(bn + colloc) * 1024 + bm + seg + 8) = o1;
    } else {
#pragma unroll
        for (int mt = 0; mt < 2; ++mt)
#pragma unroll
            for (int nt = 0; nt < 2; ++nt)
#pragma unroll
                for (int r = 0; r < 4; ++r) {
                    int row = bm + wm + mt * 16 + quad * 4 + r;
                    int col = bn + wn + nt * 16 + l16;
                    float bb = (col < 256) ? qb[col] : kb[col - 256];
                    qk[(size_t)row * QKN + col] =
                        expf(fminf(fmaxf(acc[mt][nt][r] + bb, -10.f), 10.f));
                }
    }
}

// ---------------------------------------------------------------------------
// Split-K GEMM writing fp32 partials. STRIP: XCD swizzle.
// ---------------------------------------------------------------------------
template <int STRIP>
__global__ __launch_bounds__(256) void gemm_split(const __hip_bfloat16* __restrict__ A,
                                                  const __hip_bfloat16* __restrict__ Bt,
                                                  float* __restrict__ part,
                                                  int M, int N, int K, int Ksub) {
    __shared__ __align__(16) __hip_bfloat16 As[64 * 128];
    __shared__ __align__(16) __hip_bfloat16 Bs[64 * 128];
    const int tid = threadIdx.x;
    const int w = tid >> 6, lane = tid & 63;
    const int wm = (w >> 1) * 32, wn = (w & 1) * 32;
    const int quad = lane >> 4, l16 = lane & 15;
    int bid = blockIdx.x;
    int r = bid >> 3;
    int bx = (bid & 7) * STRIP + (r % STRIP);
    int by = r / STRIP;
    const int bm = by * 64, bn = bx * 64;
    const int kz = blockIdx.z;
    floatx4 acc[2][2];
#pragma unroll
    for (int i = 0; i < 2; ++i)
#pragma unroll
        for (int j = 0; j < 2; ++j) acc[i][j] = (floatx4)0.f;
    gemm_core(A, Bt, K, bm, bn, kz * Ksub, kz * Ksub + Ksub, As, Bs, acc);
#pragma unroll
    for (int mt = 0; mt < 2; ++mt)
#pragma unroll
        for (int nt = 0; nt < 2; ++nt)
#pragma unroll
            for (int rr = 0; rr < 4; ++rr) {
                int row = bm + wm + mt * 16 + quad * 4 + rr;
                int col = bn + wn + nt * 16 + l16;
                part[((size_t)kz * M + row) * N + col] = acc[mt][nt][rr];
            }
}

__global__ __launch_bounds__(256) void w1red(const float* __restrict__ part,
                                             const float* __restrict__ b1,
                                             __hip_bfloat16* __restrict__ h1) {
    size_t e = ((size_t)blockIdx.x * 256 + threadIdx.x) * 4;
    const size_t MN = (size_t)L_SEQ * F_DIM;
    float4 p0 = *(const float4*)(part + e);
    float4 p1 = *(const float4*)(part + MN + e);
    float4 bb = *(const float4*)(b1 + (e & (F_DIM - 1)));
    h1[e + 0] = (__hip_bfloat16)fmaxf(p0.x + p1.x + bb.x, 0.f);
    h1[e + 1] = (__hip_bfloat16)fmaxf(p0.y + p1.y + bb.y, 0.f);
    h1[e + 2] = (__hip_bfloat16)fmaxf(p0.z + p1.z + bb.z, 0.f);
    h1[e + 3] = (__hip_bfloat16)fmaxf(p0.w + p1.w + bb.w, 0.f);
}

__global__ __launch_bounds__(256) void w2red(const float* __restrict__ part,
                                             const float* __restrict__ b2,
                                             const float* __restrict__ x,
                                             float* __restrict__ out) {
    size_t e = ((size_t)blockIdx.x * 256 + threadIdx.x) * 4;
    const size_t MN = (size_t)L_SEQ * D_DIM;
    float4 v0 = *(const float4*)(part + e);
    float4 v1 = *(const float4*)(part + MN + e);
    float4 v2 = *(const float4*)(part + 2 * MN + e);
    float4 v3 = *(const float4*)(part + 3 * MN + e);
    float4 bb = *(const float4*)(b2 + (e & 511));
    float4 xx = *(const float4*)(x + e);
    float4 r;
    r.x = fmaxf(v0.x + v1.x + v2.x + v3.x + bb.x, 0.f) + xx.x;
    r.y = fmaxf(v0.y + v1.y + v2.y + v3.y + bb.y, 0.f) + xx.y;
    r.z = fmaxf(v0.z + v1.z + v2.z + v3.z + bb.z, 0.f) + xx.z;
    r.w = fmaxf(v0.w + v1.w + v2.w + v3.w + bb.w, 0.f) + xx.w;
    *(float4*)(out + e) = r;
}

// ---------------------------------------------------------------------------
// kvchunk (MFMA): S[c][h][d][a] = sum_l k[c,l,a]*vT[h*512+d][c*64+l].
// B-fragments read straight from global vT. Ka chunk sums on dq==0.
// grid (NC, H, 4).
// ---------------------------------------------------------------------------
__global__ __launch_bounds__(256) void kvchunk_kernel(const float* __restrict__ qk,
                                                      const __hip_bfloat16* __restrict__ vT,
                                                      float* __restrict__ S,
                                                      float* __restrict__ Ka) {
    int c = blockIdx.x, h = blockIdx.y, dq = blockIdx.z;
    int tid = threadIdx.x;
    __shared__ __align__(16) __hip_bfloat16 kaT[32][72];  // [a][l]
    __shared__ __align__(16) float St[128][36];           // [d][a] fp32
    for (int e = tid; e < 2048; e += 256) {
        int l = e >> 5, a = e & 31;
        kaT[a][l] = (__hip_bfloat16)qk[(c * CH + l) * QKN + 256 + a * 8 + h];
    }
    __syncthreads();
    int w = tid >> 6, lane = tid & 63, quad = lane >> 4, l16 = lane & 15;
    floatx4 acc[2][2];
#pragma unroll
    for (int i = 0; i < 2; ++i)
#pragma unroll
        for (int j = 0; j < 2; ++j) acc[i][j] = (floatx4)0.f;
#pragma unroll
    for (int ks = 0; ks < 2; ++ks) {
        short8 af[2], bfr[2];
#pragma unroll
        for (int mt = 0; mt < 2; ++mt)
            af[mt] = *(const short8*)&kaT[mt * 16 + l16][ks * 32 + quad * 8];
#pragma unroll
        for (int nt = 0; nt < 2; ++nt)
            bfr[nt] = *(const short8*)(vT + (size_t)(h * 512 + dq * 128 + w * 32 + nt * 16 + l16) * 1024
                                       + c * 64 + ks * 32 + quad * 8);
#pragma unroll
        for (int mt = 0; mt < 2; ++mt)
#pragma unroll
            for (int nt = 0; nt < 2; ++nt)
                acc[mt][nt] = __builtin_amdgcn_mfma_f32_16x16x32_bf16(
                    af[mt], bfr[nt], acc[mt][nt], 0, 0, 0);
    }
#pragma unroll
    for (int mt = 0; mt < 2; ++mt)
#pragma unroll
        for (int nt = 0; nt < 2; ++nt)
            *(floatx4*)&St[w * 32 + nt * 16 + l16][mt * 16 + quad * 4] = acc[mt][nt];
    __syncthreads();
    int d = tid >> 1, aseg = (tid & 1) * 16;
    float* dst = S + (size_t)((c * 8 + h) * 512 + dq * 128 + d) * 32 + aseg;
    const float* src = &St[d][aseg];
#pragma unroll
    for (int j = 0; j < 4; ++j)
        *(float4*)(dst + j * 4) = *(const float4*)(src + j * 4);
    if (dq == 0 && tid < 32) {
        float s = 0.f;
        for (int l = 0; l < CH; ++l) s += (float)kaT[tid][l];
        Ka[c * AH + tid * 8 + h] = s;
    }
}

// ---------------------------------------------------------------------------
// scan: pure element-wise exclusive chunk prefix (S fp32 -> P2 bf16),
// fully coalesced, no LDS. Block 0 also scans Ka -> KaP.
// ---------------------------------------------------------------------------
__global__ __launch_bounds__(256) void scan_kernel(const float* __restrict__ S,
                                                   const float* __restrict__ Ka,
                                                   __hip_bfloat16* __restrict__ P2,
                                                   float* __restrict__ KaP) {
    size_t j = ((size_t)blockIdx.x * 256 + threadIdx.x) * 4;
    const size_t CS = 8 * 512 * 32;
    float4 run = {0.f, 0.f, 0.f, 0.f};
    for (int c = 0; c < NC; ++c) {
        __hip_bfloat16 o[4] = {(__hip_bfloat16)run.x, (__hip_bfloat16)run.y,
                               (__hip_bfloat16)run.z, (__hip_bfloat16)run.w};
        *(short4v*)&P2[c * CS + j] = *(short4v*)o;
        float4 sv = *(const float4*)(S + c * CS + j);
        run.x += sv.x; run.y += sv.y; run.z += sv.z; run.w += sv.w;
    }
    if (blockIdx.x == 0) {
        int t = threadIdx.x;  // a = t>>3, h = t&7
        float rk = 0.f;
        for (int c = 0; c < NC; ++c) {
            KaP[c * AH + t] = rk;
            rk += Ka[c * AH + t];
        }
    }
}

// ---------------------------------------------------------------------------
// passC (MFMA): qkv = mask(Q K^T) V + Q P ; den = rowsum(mask) + q.KaP
// V-fragments from global vT; P2 from global. grid (NC, H, 4).
// ---------------------------------------------------------------------------
__global__ __launch_bounds__(256) void passC_kernel(const float* __restrict__ qk,
                                                    const __hip_bfloat16* __restrict__ vT,
                                                    const __hip_bfloat16* __restrict__ P2,
                                                    const float* __restrict__ KaP,
                                                    __hip_bfloat16* __restrict__ qkv,
                                                    float* __restrict__ den) {
    int c = blockIdx.x, h = blockIdx.y, dq = blockIdx.z;
    int tid = threadIdx.x;
    __shared__ __align__(16) __hip_bfloat16 qa[64][40];   // [l][a]
    __shared__ __align__(16) __hip_bfloat16 ka[64][40];   // [l'][a]
    __shared__ __align__(16) __hip_bfloat16 Sc[64][72];   // [l][l']
    __shared__ float KaPs[32];
    for (int e = tid; e < 2048; e += 256) {
        int l = e >> 5, a = e & 31;
        int gi = (c * CH + l) * QKN + a * 8 + h;
        qa[l][a] = (__hip_bfloat16)qk[gi];
        ka[l][a] = (__hip_bfloat16)qk[gi + 256];
    }
    if (dq == 0 && tid < 32) KaPs[tid] = KaP[c * AH + tid * 8 + h];
    __syncthreads();
    int w = tid >> 6, lane = tid & 63, quad = lane >> 4, l16 = lane & 15;
    // Phase 1: QK^T for this wave's 16-row strip
    short8 afq = *(const short8*)&qa[w * 16 + l16][quad * 8];
    floatx4 sacc[4];
#pragma unroll
    for (int nt = 0; nt < 4; ++nt) sacc[nt] = (floatx4)0.f;
#pragma unroll
    for (int nt = 0; nt < 4; ++nt) {
        short8 bfr = *(const short8*)&ka[nt * 16 + l16][quad * 8];
        sacc[nt] = __builtin_amdgcn_mfma_f32_16x16x32_bf16(afq, bfr, sacc[nt], 0, 0, 0);
    }
#pragma unroll
    for (int nt = 0; nt < 4; ++nt)
#pragma unroll
        for (int r = 0; r < 4; ++r) {
            int l = w * 16 + quad * 4 + r;
            int lp = nt * 16 + l16;
            Sc[l][lp] = (__hip_bfloat16)((lp <= l) ? sacc[nt][r] : 0.f);
        }
    __syncthreads();
    // Phase 2: den (dq==0, wave 0)
    if (dq == 0 && tid < 64) {
        int l = tid;
        float s = 0.f;
        for (int lp = 0; lp <= l; ++lp) s += (float)Sc[l][lp];
        for (int a = 0; a < A_DIM; ++a) s += (float)qa[l][a] * KaPs[a];
        den[(c * CH + l) * H_DIM + h] = s;
    }
    // Phase 3: qkv = Q @ P2 + Sc @ V
    floatx4 acc[8];
#pragma unroll
    for (int nt = 0; nt < 8; ++nt) acc[nt] = (floatx4)0.f;
#pragma unroll
    for (int nt = 0; nt < 8; ++nt) {
        short8 pb = *(const short8*)(P2 + ((size_t)((c * 8 + h) * 512 + dq * 128 + nt * 16 + l16)) * 32 + quad * 8);
        acc[nt] = __builtin_amdgcn_mfma_f32_16x16x32_bf16(afq, pb, acc[nt], 0, 0, 0);
    }
#pragma unroll
    for (int ks = 0; ks < 2; ++ks) {
        short8 afs = *(const short8*)&Sc[w * 16 + l16][ks * 32 + quad * 8];
#pragma unroll
        for (int nt = 0; nt < 8; ++nt) {
            short8 bfr = *(const short8*)(vT + (size_t)(h * 512 + dq * 128 + nt * 16 + l16) * 1024
                                          + c * 64 + ks * 32 + quad * 8);
            acc[nt] = __builtin_amdgcn_mfma_f32_16x16x32_bf16(afs, bfr, acc[nt], 0, 0, 0);
        }
    }
#pragma unroll
    for (int nt = 0; nt < 8; ++nt)
#pragma unroll
        for (int r = 0; r < 4; ++r) {
            int l = w * 16 + quad * 4 + r;
            int d = dq * 128 + nt * 16 + l16;
            qkv[(size_t)(c * CH + l) * DH + h * D_DIM + d] = (__hip_bfloat16)acc[nt][r];
        }
}

// ---------------------------------------------------------------------------
// LN1 over (D,H) + residual. qkv bf16 [l][h*D+d]; y bf16 [l][d*H+h].
// ---------------------------------------------------------------------------
__global__ __launch_bounds__(256) void ln1_kernel(const __hip_bfloat16* __restrict__ qkv,
                                                  const float* __restrict__ den,
                                                  const float* __restrict__ x,
                                                  const float* __restrict__ w,
                                                  const float* __restrict__ b,
                                                  __hip_bfloat16* __restrict__ y) {
    int l = blockIdx.x, tid = threadIdx.x;
    __shared__ float dsh[8];
    __shared__ float yl[DH];
    __shared__ float red[8];
    if (tid < 8) dsh[tid] = den[l * H_DIM + tid];
    __syncthreads();
    float t[16];
    float s = 0.f, s2 = 0.f;
#pragma unroll
    for (int j = 0; j < 16; ++j) {
        int e = j * 256 + tid;
        float val = (float)qkv[(size_t)l * DH + e] / dsh[e >> 9];
        t[j] = val;
        s += val;
        s2 += val * val;
    }
    for (int off = 32; off > 0; off >>= 1) {
        s += __shfl_down(s, off);
        s2 += __shfl_down(s2, off);
    }
    int lane = tid & 63, wid = tid >> 6;
    if (lane == 0) { red[wid] = s; red[4 + wid] = s2; }
    __syncthreads();
    float ts = red[0] + red[1] + red[2] + red[3];
    float t2 = red[4] + red[5] + red[6] + red[7];
    float mu = ts / (float)DH;
    float var = t2 / (float)DH - mu * mu;
    float rs = rsqrtf(var + EPS_LN);
#pragma unroll
    for (int j = 0; j < 16; ++j) {
        int e = j * 256 + tid;
        int h = e >> 9, d = e & 511;
        int dh = d * H_DIM + h;
        yl[dh] = x[l * D_DIM + d] + (t[j] - mu) * rs * w[dh] + b[dh];
    }
    __syncthreads();
#pragma unroll
    for (int j = 0; j < 16; ++j) {
        int e = j * 256 + tid;
        y[(size_t)l * DH + e] = (__hip_bfloat16)yl[e];
    }
}

// ---------------------------------------------------------------------------
// Launch
// ---------------------------------------------------------------------------
extern "C" void kernel_launch(void* const* d_in, const int* in_sizes, int n_in,
                              void* d_out, int out_size, void* d_ws, size_t ws_size,
                              hipStream_t stream) {
    const float* x     = (const float*)d_in[0];
    const float* ln0_w = (const float*)d_in[1];
    const float* ln0_b = (const float*)d_in[2];
    const float* ln1_w = (const float*)d_in[3];
    const float* ln1_b = (const float*)d_in[4];
    const float* qw    = (const float*)d_in[5];
    const float* qb    = (const float*)d_in[6];
    const float* kw    = (const float*)d_in[7];
    const float* kb    = (const float*)d_in[8];
    const float* vw    = (const float*)d_in[9];
    const float* vb    = (const float*)d_in[10];
    const float* w1    = (const float*)d_in[11];
    const float* b1    = (const float*)d_in[12];
    const float* w2    = (const float*)d_in[13];
    const float* b2    = (const float*)d_in[14];
    float* out = (float*)d_out;

    char* ws = (char*)d_ws;
    __hip_bfloat16* xn_bf = (__hip_bfloat16*)(ws + 0);         // 1 MB
    __hip_bfloat16* xbf   = (__hip_bfloat16*)(ws + 1048576);   // 1 MB
    __hip_bfloat16* qkwt  = (__hip_bfloat16*)(ws + 2097152);   // 0.5 MB
    __hip_bfloat16* vwt   = (__hip_bfloat16*)(ws + 2621440);   // 4 MB
    __hip_bfloat16* w1t   = (__hip_bfloat16*)(ws + 6815744);   // 16 MB
    __hip_bfloat16* w2t   = (__hip_bfloat16*)(ws + 23592960);  // 2 MB
    float* qk  = (float*)(ws + 25690112);                      // 2 MB
    __hip_bfloat16* vT = (__hip_bfloat16*)(ws + 27787264);     // 8 MB [h*512+d][l]
    float* S   = (float*)(ws + 36175872);                      // 8 MB [c][h][d][a]
    __hip_bfloat16* P2 = (__hip_bfloat16*)(ws + 44564480);     // 4 MB [c][h][d][a]
    __hip_bfloat16* qkvb = (__hip_bfloat16*)(ws + 52953088);   // 8 MB
    float* Ka  = (float*)(ws + 61341696);                      // 16 KB
    float* den = (float*)(ws + 61358080);                      // 32 KB
    float* KaP = (float*)(ws + 61390848);                      // 16 KB
    float* w1part = (float*)(ws + 61440000);                   // 16 MB
    __hip_bfloat16* y  = (__hip_bfloat16*)(ws + 44564480);  // alias: P2 dead after passC
    __hip_bfloat16* h1 = (__hip_bfloat16*)S;                // alias: S dead after scan
    float* w2part = (float*)qkvb;                           // alias: qkvb dead after ln1

    prep_kernel<<<12544, 256, 0, stream>>>(x, ln0_w, ln0_b, qw, kw, vw, w1, w2,
                                           xn_bf, xbf, qkwt, vwt, w1t, w2t);
    qkv_gemm<<<1152, 256, 0, stream>>>(xn_bf, xbf, qkwt, vwt, qb, kb, vb, qk, vT);
    // MFMA chunked scan (transpose-free)
    kvchunk_kernel<<<dim3(NC, H_DIM, 4), 256, 0, stream>>>(qk, vT, S, Ka);
    scan_kernel<<<128, 256, 0, stream>>>(S, Ka, P2, KaP);
    passC_kernel<<<dim3(NC, H_DIM, 4), 256, 0, stream>>>(qk, vT, P2, KaP, qkvb, den);
    // LN1 + residual -> y bf16
    ln1_kernel<<<L_SEQ, 256, 0, stream>>>(qkvb, den, x, ln1_w, ln1_b, y);
    // MLP
    gemm_split<4><<<dim3(512, 1, 2), 256, 0, stream>>>(y, w1t, w1part,
                                                       L_SEQ, F_DIM, DH, DH / 2);
    w1red<<<(L_SEQ * F_DIM) / 1024, 256, 0, stream>>>(w1part, b1, h1);
    gemm_split<1><<<dim3(128, 1, 4), 256, 0, stream>>>(h1, w2t, w2part,
                                                       L_SEQ, D_DIM, F_DIM, F_DIM / 4);
    w2red<<<(L_SEQ * D_DIM) / 1024, 256, 0, stream>>>(w2part, b2, x, out);

    (void)in_sizes; (void)n_in; (void)out_size; (void)ws_size;
}

// Round 8
// 206.160 us; speedup vs baseline: 1.2949x; 1.0346x over previous
//
#include <hip/hip_runtime.h>
#include <hip/hip_bf16.h>
#include <math.h>

#define L_SEQ 1024
#define D_DIM 512
#define A_DIM 32
#define H_DIM 8
#define F_DIM 2048
#define AH 256
#define DH 4096
#define NC 16
#define CH 64
#define EPS_LN 1e-5f

typedef __attribute__((ext_vector_type(8))) short short8;
typedef __attribute__((ext_vector_type(4))) short short4v;
typedef __attribute__((ext_vector_type(4))) float floatx4;

#define ASYNC_COPY16(gp, lp)                                                     \
    __builtin_amdgcn_global_load_lds(                                            \
        (const __attribute__((address_space(1))) void*)(const void*)(gp),        \
        (__attribute__((address_space(3))) void*)(void*)(lp), 16, 0, 0)

// ---------------------------------------------------------------------------
// prep: fused LN0 (+bf16 casts of x), weight transposes, ln1 w/b permute.
// w1 K-dim is permuted (k' = h*512+d  <->  k = d*8+h) so y can stay in scan
// layout and ln1 needs no reorder.
// ---------------------------------------------------------------------------
__global__ __launch_bounds__(256) void prep_kernel(const float* __restrict__ x,
                                                   const float* __restrict__ ln0w,
                                                   const float* __restrict__ ln0b,
                                                   const float* __restrict__ ln1w,
                                                   const float* __restrict__ ln1b,
                                                   const float* __restrict__ qw,
                                                   const float* __restrict__ kw,
                                                   const float* __restrict__ vw,
                                                   const float* __restrict__ w1,
                                                   const float* __restrict__ w2,
                                                   __hip_bfloat16* __restrict__ xn,
                                                   __hip_bfloat16* __restrict__ xb,
                                                   __hip_bfloat16* __restrict__ qkwt,
                                                   __hip_bfloat16* __restrict__ vwt,
                                                   __hip_bfloat16* __restrict__ w1t,
                                                   __hip_bfloat16* __restrict__ w2t,
                                                   float* __restrict__ wp,
                                                   float* __restrict__ bp) {
    __shared__ float tt[32][33];
    __shared__ float red[8];
    int bid = blockIdx.x;
    int tid = threadIdx.x;
    if (bid < 1024) {
        int l = bid;
        float v0 = x[l * D_DIM + tid];
        float v1 = x[l * D_DIM + 256 + tid];
        float s = v0 + v1, s2 = v0 * v0 + v1 * v1;
        for (int off = 32; off > 0; off >>= 1) {
            s += __shfl_down(s, off);
            s2 += __shfl_down(s2, off);
        }
        int lane = tid & 63, wid = tid >> 6;
        if (lane == 0) { red[wid] = s; red[4 + wid] = s2; }
        __syncthreads();
        float ts = red[0] + red[1] + red[2] + red[3];
        float t2 = red[4] + red[5] + red[6] + red[7];
        float mu = ts / (float)D_DIM;
        float var = t2 / (float)D_DIM - mu * mu;
        float rs = rsqrtf(var + EPS_LN);
        xn[l * D_DIM + tid]       = (__hip_bfloat16)((v0 - mu) * rs * ln0w[tid] + ln0b[tid]);
        xn[l * D_DIM + 256 + tid] = (__hip_bfloat16)((v1 - mu) * rs * ln0w[256 + tid] + ln0b[256 + tid]);
        xb[l * D_DIM + tid]       = (__hip_bfloat16)v0;
        xb[l * D_DIM + 256 + tid] = (__hip_bfloat16)v1;
        return;
    }
    if (bid == 12544) {
        // ln1 w/b permuted to [h*512+d] order
        int e0 = tid * 16;
        float o1[16], o2[16];
#pragma unroll
        for (int j = 0; j < 16; ++j) {
            int ee = e0 + j;
            int pi = ((ee & 511) << 3) | (ee >> 9);
            o1[j] = ln1w[pi];
            o2[j] = ln1b[pi];
        }
#pragma unroll
        for (int j = 0; j < 4; ++j) {
            *(float4*)(wp + e0 + j * 4) = *(float4*)&o1[j * 4];
            *(float4*)(bp + e0 + j * 4) = *(float4*)&o2[j * 4];
        }
        return;
    }
    const float* in;
    __hip_bfloat16* out;
    int R, C, mode = 0, t;
    if (bid < 1152)      { t = bid - 1024;  in = qw; out = qkwt;                      R = 512;  C = 256; }
    else if (bid < 1280) { t = bid - 1152;  in = kw; out = qkwt + (size_t)AH * D_DIM; R = 512;  C = 256; }
    else if (bid < 3328) { t = bid - 1280;  in = vw; out = vwt;  mode = 1;            R = 512;  C = 4096; }
    else if (bid < 11520){ t = bid - 3328;  in = w1; out = w1t;  mode = 2;            R = 4096; C = 2048; }
    else                 { t = bid - 11520; in = w2; out = w2t;                       R = 2048; C = 512; }
    int ctiles = C >> 5;
    int cx = t % ctiles, cy = t / ctiles;
    int tx = tid & 31, ti = tid >> 5;
    int r0 = cy * 32, c0 = cx * 32;
#pragma unroll
    for (int ii = 0; ii < 4; ++ii) {
        int rr = r0 + ti + ii * 8;
        if (mode == 2) rr = ((rr & 511) << 3) | (rr >> 9);  // w1 K-perm
        tt[ti + ii * 8][tx] = in[(size_t)rr * C + c0 + tx];
    }
    __syncthreads();
#pragma unroll
    for (int ii = 0; ii < 4; ++ii) {
        int c = c0 + ti + ii * 8;
        int orow = (mode == 1) ? (((c & 7) << 9) | (c >> 3)) : c;
        out[(size_t)orow * R + r0 + tx] = (__hip_bfloat16)tt[tx][ti + ii * 8];
    }
}

// ---------------------------------------------------------------------------
// Shared BK=128 MFMA core.
// ---------------------------------------------------------------------------
__device__ __forceinline__ void gemm_core(const __hip_bfloat16* __restrict__ A,
                                          const __hip_bfloat16* __restrict__ Bt,
                                          int K, int bm, int bn, int k_beg, int k_end,
                                          __hip_bfloat16* As, __hip_bfloat16* Bs,
                                          floatx4 acc[2][2]) {
    const int tid = threadIdx.x;
    const int w = tid >> 6, lane = tid & 63;
    const int wm = (w >> 1) * 32, wn = (w & 1) * 32;
    const int quad = lane >> 4, l16 = lane & 15;
    const int srow = tid >> 4, sslot = tid & 15;
    const int scg = sslot ^ srow;
    for (int k0 = k_beg; k0 < k_end; k0 += 128) {
        __syncthreads();
#pragma unroll
        for (int j = 0; j < 4; ++j) {
            ASYNC_COPY16(A + (size_t)(bm + j * 16 + srow) * K + k0 + scg * 8,
                         As + j * 2048 + w * 512);
            ASYNC_COPY16(Bt + (size_t)(bn + j * 16 + srow) * K + k0 + scg * 8,
                         Bs + j * 2048 + w * 512);
        }
        __syncthreads();
#pragma unroll
        for (int ks = 0; ks < 4; ++ks) {
            short8 af[2], bfr[2];
#pragma unroll
            for (int mt = 0; mt < 2; ++mt) {
                int rr = wm + mt * 16 + l16;
                af[mt] = *(const short8*)(As + rr * 128 + (((ks * 4 + quad) ^ (rr & 15)) * 8));
            }
#pragma unroll
            for (int nt = 0; nt < 2; ++nt) {
                int rr = wn + nt * 16 + l16;
                bfr[nt] = *(const short8*)(Bs + rr * 128 + (((ks * 4 + quad) ^ (rr & 15)) * 8));
            }
#pragma unroll
            for (int mt = 0; mt < 2; ++mt)
#pragma unroll
                for (int nt = 0; nt < 2; ++nt)
                    acc[mt][nt] = __builtin_amdgcn_mfma_f32_16x16x32_bf16(
                        af[mt], bfr[nt], acc[mt][nt], 0, 0, 0);
        }
    }
}

// ---------------------------------------------------------------------------
// Fused q|k and v projections. v -> vT[h*512+d][l] (bf16, bounce);
// q,k -> q2/k2 [h][l][a] bf16 (exp-clip applied, bounce).
// ---------------------------------------------------------------------------
__global__ __launch_bounds__(256) void qkv_gemm(const __hip_bfloat16* __restrict__ xn,
                                                const __hip_bfloat16* __restrict__ xb,
                                                const __hip_bfloat16* __restrict__ qkwt,
                                                const __hip_bfloat16* __restrict__ vwt,
                                                const float* __restrict__ qb,
                                                const float* __restrict__ kb,
                                                const float* __restrict__ vb,
                                                __hip_bfloat16* __restrict__ q2,
                                                __hip_bfloat16* __restrict__ k2,
                                                __hip_bfloat16* __restrict__ vT) {
    __shared__ __align__(16) __hip_bfloat16 As[64 * 128];
    __shared__ __align__(16) __hip_bfloat16 Bs[64 * 128];
    const int tid = threadIdx.x;
    const int w = tid >> 6, lane = tid & 63;
    const int wm = (w >> 1) * 32, wn = (w & 1) * 32;
    const int quad = lane >> 4, l16 = lane & 15;
    int bid = blockIdx.x;
    bool isv = bid < 1024;
    const __hip_bfloat16 *A, *Bt;
    int bx, by;
    if (isv) {
        int r = bid >> 3;
        bx = (bid & 7) * 8 + (r & 7);
        by = r >> 3;
        A = xb; Bt = vwt;
    } else {
        int b2 = bid - 1024;
        bx = b2 & 7; by = b2 >> 3;
        A = xn; Bt = qkwt;
    }
    const int bm = by * 64, bn = bx * 64;
    floatx4 acc[2][2];
#pragma unroll
    for (int i = 0; i < 2; ++i)
#pragma unroll
        for (int j = 0; j < 2; ++j) acc[i][j] = (floatx4)0.f;
    gemm_core(A, Bt, D_DIM, bm, bn, 0, D_DIM, As, Bs, acc);
    if (isv) {
        // LDS-bounce transpose: Ct[col 64][row 72pad] then coalesced vT write
        __syncthreads();
        __hip_bfloat16* Ct = As;
#pragma unroll
        for (int mt = 0; mt < 2; ++mt)
#pragma unroll
            for (int nt = 0; nt < 2; ++nt) {
                int col = bn + wn + nt * 16 + l16;
                int bi = ((col & 511) << 3) | (col >> 9);
                float bbv = vb[bi];
                __hip_bfloat16 tmp[4];
#pragma unroll
                for (int r = 0; r < 4; ++r)
                    tmp[r] = (__hip_bfloat16)(acc[mt][nt][r] + bbv);
                *(short4v*)&Ct[(wn + nt * 16 + l16) * 72 + wm + mt * 16 + quad * 4] =
                    *(short4v*)tmp;
            }
        __syncthreads();
        int colloc = tid >> 2, seg = (tid & 3) * 16;
        short8 o0 = *(const short8*)&Ct[colloc * 72 + seg];
        short8 o1 = *(const short8*)&Ct[colloc * 72 + seg + 8];
        *(short8*)(vT + (size_t)(bn + colloc) * 1024 + bm + seg) = o0;
        *(short8*)(vT + (size_t)(bn + colloc) * 1024 + bm + seg + 8) = o1;
    } else {
        // q/k tile: exp(clip(+bias)) bf16, bounce to [h][l][a]
        __syncthreads();
        __hip_bfloat16* q2t = As;  // [h][l 64][a 8] -> ((h*64+l)<<3)+a
        bool isq = bn < 256;
        const float* bias = isq ? qb : kb;
        int cb = isq ? bn : bn - 256;
#pragma unroll
        for (int mt = 0; mt < 2; ++mt)
#pragma unroll
            for (int nt = 0; nt < 2; ++nt) {
                int colloc = wn + nt * 16 + l16;
                float bb = bias[cb + colloc];
                int hh = colloc & 7, aa = colloc >> 3;
#pragma unroll
                for (int r = 0; r < 4; ++r) {
                    int rowloc = wm + mt * 16 + quad * 4 + r;
                    float val = expf(fminf(fmaxf(acc[mt][nt][r] + bb, -10.f), 10.f));
                    q2t[((hh * 64 + rowloc) << 3) + aa] = (__hip_bfloat16)val;
                }
            }
        __syncthreads();
        __hip_bfloat16* dst = isq ? q2 : k2;
        int a0 = cb >> 3;
#pragma unroll
        for (int j = 0; j < 2; ++j) {
            int p = tid + j * 256;
            int hh = p >> 6, ll = p & 63;
            short8 o = *(const short8*)&q2t[(hh * 64 + ll) << 3];
            *(short8*)(dst + (size_t)(hh * 1024 + bm + ll) * 32 + a0) = o;
        }
    }
}

// ---------------------------------------------------------------------------
// Split-K GEMM writing fp32 partials. STRIP: XCD swizzle.
// ---------------------------------------------------------------------------
template <int STRIP>
__global__ __launch_bounds__(256) void gemm_split(const __hip_bfloat16* __restrict__ A,
                                                  const __hip_bfloat16* __restrict__ Bt,
                                                  float* __restrict__ part,
                                                  int M, int N, int K, int Ksub) {
    __shared__ __align__(16) __hip_bfloat16 As[64 * 128];
    __shared__ __align__(16) __hip_bfloat16 Bs[64 * 128];
    const int tid = threadIdx.x;
    const int w = tid >> 6, lane = tid & 63;
    const int wm = (w >> 1) * 32, wn = (w & 1) * 32;
    const int quad = lane >> 4, l16 = lane & 15;
    int bid = blockIdx.x;
    int r = bid >> 3;
    int bx = (bid & 7) * STRIP + (r % STRIP);
    int by = r / STRIP;
    const int bm = by * 64, bn = bx * 64;
    const int kz = blockIdx.z;
    floatx4 acc[2][2];
#pragma unroll
    for (int i = 0; i < 2; ++i)
#pragma unroll
        for (int j = 0; j < 2; ++j) acc[i][j] = (floatx4)0.f;
    gemm_core(A, Bt, K, bm, bn, kz * Ksub, kz * Ksub + Ksub, As, Bs, acc);
#pragma unroll
    for (int mt = 0; mt < 2; ++mt)
#pragma unroll
        for (int nt = 0; nt < 2; ++nt)
#pragma unroll
            for (int rr = 0; rr < 4; ++rr) {
                int row = bm + wm + mt * 16 + quad * 4 + rr;
                int col = bn + wn + nt * 16 + l16;
                part[((size_t)kz * M + row) * N + col] = acc[mt][nt][rr];
            }
}

__global__ __launch_bounds__(256) void w1red(const float* __restrict__ part,
                                             const float* __restrict__ b1,
                                             __hip_bfloat16* __restrict__ h1) {
    size_t e = ((size_t)blockIdx.x * 256 + threadIdx.x) * 4;
    const size_t MN = (size_t)L_SEQ * F_DIM;
    float4 p0 = *(const float4*)(part + e);
    float4 p1 = *(const float4*)(part + MN + e);
    float4 bb = *(const float4*)(b1 + (e & (F_DIM - 1)));
    h1[e + 0] = (__hip_bfloat16)fmaxf(p0.x + p1.x + bb.x, 0.f);
    h1[e + 1] = (__hip_bfloat16)fmaxf(p0.y + p1.y + bb.y, 0.f);
    h1[e + 2] = (__hip_bfloat16)fmaxf(p0.z + p1.z + bb.z, 0.f);
    h1[e + 3] = (__hip_bfloat16)fmaxf(p0.w + p1.w + bb.w, 0.f);
}

__global__ __launch_bounds__(256) void w2red(const float* __restrict__ part,
                                             const float* __restrict__ b2,
                                             const float* __restrict__ x,
                                             float* __restrict__ out) {
    size_t e = ((size_t)blockIdx.x * 256 + threadIdx.x) * 4;
    const size_t MN = (size_t)L_SEQ * D_DIM;
    float4 v0 = *(const float4*)(part + e);
    float4 v1 = *(const float4*)(part + MN + e);
    float4 v2 = *(const float4*)(part + 2 * MN + e);
    float4 v3 = *(const float4*)(part + 3 * MN + e);
    float4 bb = *(const float4*)(b2 + (e & 511));
    float4 xx = *(const float4*)(x + e);
    float4 r;
    r.x = fmaxf(v0.x + v1.x + v2.x + v3.x + bb.x, 0.f) + xx.x;
    r.y = fmaxf(v0.y + v1.y + v2.y + v3.y + bb.y, 0.f) + xx.y;
    r.z = fmaxf(v0.z + v1.z + v2.z + v3.z + bb.z, 0.f) + xx.z;
    r.w = fmaxf(v0.w + v1.w + v2.w + v3.w + bb.w, 0.f) + xx.w;
    *(float4*)(out + e) = r;
}

// ---------------------------------------------------------------------------
// kvchunk (MFMA): S[c][h][d][a] = sum_l k2[h][c*64+l][a] * vT[h*512+d][c*64+l]
// grid (NC, H, 4).
// ---------------------------------------------------------------------------
__global__ __launch_bounds__(256) void kvchunk_kernel(const __hip_bfloat16* __restrict__ k2,
                                                      const __hip_bfloat16* __restrict__ vT,
                                                      float* __restrict__ S,
                                                      float* __restrict__ Ka) {
    int c = blockIdx.x, h = blockIdx.y, dq = blockIdx.z;
    int tid = threadIdx.x;
    __shared__ __align__(16) __hip_bfloat16 kaT[32][72];  // [a][l]
    __shared__ __align__(16) float St[128][36];           // [d][a]
    {
        int l = tid >> 2, a0s = (tid & 3) * 8;
        short8 kv8 = *(const short8*)(k2 + (size_t)(h * 1024 + c * 64 + l) * 32 + a0s);
#pragma unroll
        for (int j = 0; j < 8; ++j)
            kaT[a0s + j][l] = ((const __hip_bfloat16*)&kv8)[j];
    }
    __syncthreads();
    int w = tid >> 6, lane = tid & 63, quad = lane >> 4, l16 = lane & 15;
    floatx4 acc[2][2];
#pragma unroll
    for (int i = 0; i < 2; ++i)
#pragma unroll
        for (int j = 0; j < 2; ++j) acc[i][j] = (floatx4)0.f;
#pragma unroll
    for (int ks = 0; ks < 2; ++ks) {
        short8 af[2], bfr[2];
#pragma unroll
        for (int mt = 0; mt < 2; ++mt)
            af[mt] = *(const short8*)&kaT[mt * 16 + l16][ks * 32 + quad * 8];
#pragma unroll
        for (int nt = 0; nt < 2; ++nt)
            bfr[nt] = *(const short8*)(vT + (size_t)(h * 512 + dq * 128 + w * 32 + nt * 16 + l16) * 1024
                                       + c * 64 + ks * 32 + quad * 8);
#pragma unroll
        for (int mt = 0; mt < 2; ++mt)
#pragma unroll
            for (int nt = 0; nt < 2; ++nt)
                acc[mt][nt] = __builtin_amdgcn_mfma_f32_16x16x32_bf16(
                    af[mt], bfr[nt], acc[mt][nt], 0, 0, 0);
    }
#pragma unroll
    for (int mt = 0; mt < 2; ++mt)
#pragma unroll
        for (int nt = 0; nt < 2; ++nt)
            *(floatx4*)&St[w * 32 + nt * 16 + l16][mt * 16 + quad * 4] = acc[mt][nt];
    __syncthreads();
    int d = tid >> 1, aseg = (tid & 1) * 16;
    float* dst = S + (size_t)((c * 8 + h) * 512 + dq * 128 + d) * 32 + aseg;
    const float* src = &St[d][aseg];
#pragma unroll
    for (int j = 0; j < 4; ++j)
        *(float4*)(dst + j * 4) = *(const float4*)(src + j * 4);
    if (dq == 0 && tid < 32) {
        float s = 0.f;
        for (int l = 0; l < CH; ++l) s += (float)kaT[tid][l];
        Ka[c * AH + tid * 8 + h] = s;
    }
}

// ---------------------------------------------------------------------------
// scan: element-wise exclusive chunk prefix (S fp32 -> P2 bf16), coalesced.
// ---------------------------------------------------------------------------
__global__ __launch_bounds__(256) void scan_kernel(const float* __restrict__ S,
                                                   const float* __restrict__ Ka,
                                                   __hip_bfloat16* __restrict__ P2,
                                                   float* __restrict__ KaP) {
    size_t j = ((size_t)blockIdx.x * 256 + threadIdx.x) * 4;
    const size_t CS = 8 * 512 * 32;
    float4 run = {0.f, 0.f, 0.f, 0.f};
    for (int c = 0; c < NC; ++c) {
        __hip_bfloat16 o[4] = {(__hip_bfloat16)run.x, (__hip_bfloat16)run.y,
                               (__hip_bfloat16)run.z, (__hip_bfloat16)run.w};
        *(short4v*)&P2[c * CS + j] = *(short4v*)o;
        float4 sv = *(const float4*)(S + c * CS + j);
        run.x += sv.x; run.y += sv.y; run.z += sv.z; run.w += sv.w;
    }
    if (blockIdx.x == 0) {
        int t = threadIdx.x;
        float rk = 0.f;
        for (int c = 0; c < NC; ++c) {
            KaP[c * AH + t] = rk;
            rk += Ka[c * AH + t];
        }
    }
}

// ---------------------------------------------------------------------------
// passC (MFMA): qkv = mask(Q K^T) V + Q P2 ; den = rowsum(mask) + q.KaP.
// Q/K fragments read DIRECT from global q2/k2 [h][l][a]. grid (NC, H, 4).
// ---------------------------------------------------------------------------
__global__ __launch_bounds__(256) void passC_kernel(const __hip_bfloat16* __restrict__ q2,
                                                    const __hip_bfloat16* __restrict__ k2,
                                                    const __hip_bfloat16* __restrict__ vT,
                                                    const __hip_bfloat16* __restrict__ P2,
                                                    const float* __restrict__ KaP,
                                                    __hip_bfloat16* __restrict__ qkv,
                                                    float* __restrict__ den) {
    int c = blockIdx.x, h = blockIdx.y, dq = blockIdx.z;
    int tid = threadIdx.x;
    __shared__ __align__(16) __hip_bfloat16 Sc[64][72];   // [l][l']
    __shared__ float KaPs[32];
    if (dq == 0 && tid < 32) KaPs[tid] = KaP[c * AH + tid * 8 + h];
    int w = tid >> 6, lane = tid & 63, quad = lane >> 4, l16 = lane & 15;
    const size_t qbase = (size_t)(h * 1024 + c * 64) * 32;
    // Phase 1: QK^T for this wave's 16-row strip
    short8 afq = *(const short8*)(q2 + qbase + (w * 16 + l16) * 32 + quad * 8);
    floatx4 sacc[4];
#pragma unroll
    for (int nt = 0; nt < 4; ++nt) sacc[nt] = (floatx4)0.f;
#pragma unroll
    for (int nt = 0; nt < 4; ++nt) {
        short8 bfr = *(const short8*)(k2 + qbase + (nt * 16 + l16) * 32 + quad * 8);
        sacc[nt] = __builtin_amdgcn_mfma_f32_16x16x32_bf16(afq, bfr, sacc[nt], 0, 0, 0);
    }
#pragma unroll
    for (int nt = 0; nt < 4; ++nt)
#pragma unroll
        for (int r = 0; r < 4; ++r) {
            int l = w * 16 + quad * 4 + r;
            int lp = nt * 16 + l16;
            Sc[l][lp] = (__hip_bfloat16)((lp <= l) ? sacc[nt][r] : 0.f);
        }
    __syncthreads();
    // Phase 2: den (dq==0, first 64 threads)
    if (dq == 0 && tid < 64) {
        int l = tid;
        float s = 0.f;
        for (int lp = 0; lp <= l; ++lp) s += (float)Sc[l][lp];
        const __hip_bfloat16* qp = q2 + qbase + l * 32;
        for (int a = 0; a < A_DIM; ++a) s += (float)qp[a] * KaPs[a];
        den[(c * CH + l) * H_DIM + h] = s;
    }
    // Phase 3: qkv = Q @ P2 + Sc @ V
    floatx4 acc[8];
#pragma unroll
    for (int nt = 0; nt < 8; ++nt) acc[nt] = (floatx4)0.f;
#pragma unroll
    for (int nt = 0; nt < 8; ++nt) {
        short8 pb = *(const short8*)(P2 + ((size_t)((c * 8 + h) * 512 + dq * 128 + nt * 16 + l16)) * 32 + quad * 8);
        acc[nt] = __builtin_amdgcn_mfma_f32_16x16x32_bf16(afq, pb, acc[nt], 0, 0, 0);
    }
#pragma unroll
    for (int ks = 0; ks < 2; ++ks) {
        short8 afs = *(const short8*)&Sc[w * 16 + l16][ks * 32 + quad * 8];
#pragma unroll
        for (int nt = 0; nt < 8; ++nt) {
            short8 bfr = *(const short8*)(vT + (size_t)(h * 512 + dq * 128 + nt * 16 + l16) * 1024
                                          + c * 64 + ks * 32 + quad * 8);
            acc[nt] = __builtin_amdgcn_mfma_f32_16x16x32_bf16(afs, bfr, acc[nt], 0, 0, 0);
        }
    }
#pragma unroll
    for (int nt = 0; nt < 8; ++nt)
#pragma unroll
        for (int r = 0; r < 4; ++r) {
            int l = w * 16 + quad * 4 + r;
            int d = dq * 128 + nt * 16 + l16;
            qkv[(size_t)(c * CH + l) * DH + h * D_DIM + d] = (__hip_bfloat16)acc[nt][r];
        }
}

// ---------------------------------------------------------------------------
// LN1 over (D,H) + residual, fully vectorized, NO reorder:
// y[l][h*512+d] = x[l][d] + (qkv/den - mu)*rs*wp + bp   (wp/bp pre-permuted)
// ---------------------------------------------------------------------------
__global__ __launch_bounds__(256) void ln1_kernel(const __hip_bfloat16* __restrict__ qkv,
                                                  const float* __restrict__ den,
                                                  const float* __restrict__ x,
                                                  const float* __restrict__ wp,
                                                  const float* __restrict__ bp,
                                                  __hip_bfloat16* __restrict__ y) {
    int l = blockIdx.x, tid = threadIdx.x;
    __shared__ float red[8];
    int h = tid >> 5;
    int e0 = tid * 16;
    int d0 = e0 & 511;
    float rden = 1.f / den[l * 8 + h];
    short8 v0 = *(const short8*)(qkv + (size_t)l * DH + e0);
    short8 v1 = *(const short8*)(qkv + (size_t)l * DH + e0 + 8);
    float vals[16];
    float s = 0.f, s2 = 0.f;
#pragma unroll
    for (int j = 0; j < 8; ++j) {
        vals[j] = (float)((const __hip_bfloat16*)&v0)[j] * rden;
        vals[8 + j] = (float)((const __hip_bfloat16*)&v1)[j] * rden;
    }
#pragma unroll
    for (int j = 0; j < 16; ++j) { s += vals[j]; s2 += vals[j] * vals[j]; }
    for (int off = 32; off > 0; off >>= 1) {
        s += __shfl_down(s, off);
        s2 += __shfl_down(s2, off);
    }
    int lane = tid & 63, wid = tid >> 6;
    if (lane == 0) { red[wid] = s; red[4 + wid] = s2; }
    __syncthreads();
    float ts = red[0] + red[1] + red[2] + red[3];
    float t2 = red[4] + red[5] + red[6] + red[7];
    float mu = ts / (float)DH;
    float var = t2 / (float)DH - mu * mu;
    float rs = rsqrtf(var + EPS_LN);
    __hip_bfloat16 o[16];
#pragma unroll
    for (int j4 = 0; j4 < 4; ++j4) {
        float4 xx = *(const float4*)(x + l * D_DIM + d0 + j4 * 4);
        float4 wv = *(const float4*)(wp + e0 + j4 * 4);
        float4 bv = *(const float4*)(bp + e0 + j4 * 4);
        o[j4 * 4 + 0] = (__hip_bfloat16)(xx.x + (vals[j4 * 4 + 0] - mu) * rs * wv.x + bv.x);
        o[j4 * 4 + 1] = (__hip_bfloat16)(xx.y + (vals[j4 * 4 + 1] - mu) * rs * wv.y + bv.y);
        o[j4 * 4 + 2] = (__hip_bfloat16)(xx.z + (vals[j4 * 4 + 2] - mu) * rs * wv.z + bv.z);
        o[j4 * 4 + 3] = (__hip_bfloat16)(xx.w + (vals[j4 * 4 + 3] - mu) * rs * wv.w + bv.w);
    }
    *(short8*)(y + (size_t)l * DH + e0) = *(short8*)&o[0];
    *(short8*)(y + (size_t)l * DH + e0 + 8) = *(short8*)&o[8];
}

// ---------------------------------------------------------------------------
// Launch
// ---------------------------------------------------------------------------
extern "C" void kernel_launch(void* const* d_in, const int* in_sizes, int n_in,
                              void* d_out, int out_size, void* d_ws, size_t ws_size,
                              hipStream_t stream) {
    const float* x     = (const float*)d_in[0];
    const float* ln0_w = (const float*)d_in[1];
    const float* ln0_b = (const float*)d_in[2];
    const float* ln1_w = (const float*)d_in[3];
    const float* ln1_b = (const float*)d_in[4];
    const float* qw    = (const float*)d_in[5];
    const float* qb    = (const float*)d_in[6];
    const float* kw    = (const float*)d_in[7];
    const float* kb    = (const float*)d_in[8];
    const float* vw    = (const float*)d_in[9];
    const float* vb    = (const float*)d_in[10];
    const float* w1    = (const float*)d_in[11];
    const float* b1    = (const float*)d_in[12];
    const float* w2    = (const float*)d_in[13];
    const float* b2    = (const float*)d_in[14];
    float* out = (float*)d_out;

    char* ws = (char*)d_ws;
    __hip_bfloat16* xn_bf = (__hip_bfloat16*)(ws + 0);         // 1 MB
    __hip_bfloat16* xbf   = (__hip_bfloat16*)(ws + 1048576);   // 1 MB
    __hip_bfloat16* qkwt  = (__hip_bfloat16*)(ws + 2097152);   // 0.5 MB
    __hip_bfloat16* vwt   = (__hip_bfloat16*)(ws + 2621440);   // 4 MB
    __hip_bfloat16* w1t   = (__hip_bfloat16*)(ws + 6815744);   // 16 MB (K-permuted)
    __hip_bfloat16* w2t   = (__hip_bfloat16*)(ws + 23592960);  // 2 MB
    __hip_bfloat16* q2    = (__hip_bfloat16*)(ws + 25690112);  // 512 KB [h][l][a]
    __hip_bfloat16* k2    = (__hip_bfloat16*)(ws + 26214400);  // 512 KB [h][l][a]
    __hip_bfloat16* vT    = (__hip_bfloat16*)(ws + 26738688);  // 8 MB [h*512+d][l]
    float* S              = (float*)(ws + 35127296);           // 8 MB [c][h][d][a]
    __hip_bfloat16* P2    = (__hip_bfloat16*)(ws + 43515904);  // 4 MB [c][h][d][a]
    __hip_bfloat16* qkvb  = (__hip_bfloat16*)(ws + 51904512);  // 8 MB
    float* Ka  = (float*)(ws + 60293120);                      // 16 KB
    float* KaP = (float*)(ws + 60309504);                      // 16 KB
    float* den = (float*)(ws + 60325888);                      // 32 KB
    float* wp  = (float*)(ws + 60358656);                      // 16 KB
    float* bp  = (float*)(ws + 60375040);                      // 16 KB
    float* w1part = (float*)(ws + 60391424);                   // 16 MB
    __hip_bfloat16* y  = P2;                 // alias: P2 dead after passC (8 MB to qkvb)
    __hip_bfloat16* h1 = (__hip_bfloat16*)S; // alias: S dead after scan
    float* w2part = (float*)qkvb;            // alias: qkvb dead after ln1

    prep_kernel<<<12545, 256, 0, stream>>>(x, ln0_w, ln0_b, ln1_w, ln1_b,
                                           qw, kw, vw, w1, w2,
                                           xn_bf, xbf, qkwt, vwt, w1t, w2t, wp, bp);
    qkv_gemm<<<1152, 256, 0, stream>>>(xn_bf, xbf, qkwt, vwt, qb, kb, vb, q2, k2, vT);
    kvchunk_kernel<<<dim3(NC, H_DIM, 4), 256, 0, stream>>>(k2, vT, S, Ka);
    scan_kernel<<<128, 256, 0, stream>>>(S, Ka, P2, KaP);
    passC_kernel<<<dim3(NC, H_DIM, 4), 256, 0, stream>>>(q2, k2, vT, P2, KaP, qkvb, den);
    ln1_kernel<<<L_SEQ, 256, 0, stream>>>(qkvb, den, x, wp, bp, y);
    gemm_split<4><<<dim3(512, 1, 2), 256, 0, stream>>>(y, w1t, w1part,
                                                       L_SEQ, F_DIM, DH, DH / 2);
    w1red<<<(L_SEQ * F_DIM) / 1024, 256, 0, stream>>>(w1part, b1, h1);
    gemm_split<1><<<dim3(128, 1, 4), 256, 0, stream>>>(h1, w2t, w2part,
                                                       L_SEQ, D_DIM, F_DIM, F_DIM / 4);
    w2red<<<(L_SEQ * D_DIM) / 1024, 256, 0, stream>>>(w2part, b2, x, out);

    (void)in_sizes; (void)n_in; (void)out_size; (void)ws_size;
}

// Round 9
// 204.636 us; speedup vs baseline: 1.3046x; 1.0074x over previous
//
#include <hip/hip_runtime.h>
#include <hip/hip_bf16.h>
#include <math.h>

#define L_SEQ 1024
#define D_DIM 512
#define A_DIM 32
#define H_DIM 8
#define F_DIM 2048
#define AH 256
#define DH 4096
#define NC 16
#define CH 64
#define EPS_LN 1e-5f

typedef __attribute__((ext_vector_type(8))) short short8;
typedef __attribute__((ext_vector_type(4))) short short4v;
typedef __attribute__((ext_vector_type(4))) float floatx4;

#define ASYNC_COPY16(gp, lp)                                                     \
    __builtin_amdgcn_global_load_lds(                                            \
        (const __attribute__((address_space(1))) void*)(const void*)(gp),        \
        (__attribute__((address_space(3))) void*)(void*)(lp), 16, 0, 0)

// ---------------------------------------------------------------------------
// prep: fused LN0 (+bf16 casts of x), weight transposes, ln1 w/b permute.
// w1 K-dim is permuted (k' = h*512+d) so y stays in scan layout.
// ---------------------------------------------------------------------------
__global__ __launch_bounds__(256) void prep_kernel(const float* __restrict__ x,
                                                   const float* __restrict__ ln0w,
                                                   const float* __restrict__ ln0b,
                                                   const float* __restrict__ ln1w,
                                                   const float* __restrict__ ln1b,
                                                   const float* __restrict__ qw,
                                                   const float* __restrict__ kw,
                                                   const float* __restrict__ vw,
                                                   const float* __restrict__ w1,
                                                   const float* __restrict__ w2,
                                                   __hip_bfloat16* __restrict__ xn,
                                                   __hip_bfloat16* __restrict__ xb,
                                                   __hip_bfloat16* __restrict__ qkwt,
                                                   __hip_bfloat16* __restrict__ vwt,
                                                   __hip_bfloat16* __restrict__ w1t,
                                                   __hip_bfloat16* __restrict__ w2t,
                                                   float* __restrict__ wp,
                                                   float* __restrict__ bp) {
    __shared__ float tt[32][33];
    __shared__ float red[8];
    int bid = blockIdx.x;
    int tid = threadIdx.x;
    if (bid < 1024) {
        int l = bid;
        float v0 = x[l * D_DIM + tid];
        float v1 = x[l * D_DIM + 256 + tid];
        float s = v0 + v1, s2 = v0 * v0 + v1 * v1;
        for (int off = 32; off > 0; off >>= 1) {
            s += __shfl_down(s, off);
            s2 += __shfl_down(s2, off);
        }
        int lane = tid & 63, wid = tid >> 6;
        if (lane == 0) { red[wid] = s; red[4 + wid] = s2; }
        __syncthreads();
        float ts = red[0] + red[1] + red[2] + red[3];
        float t2 = red[4] + red[5] + red[6] + red[7];
        float mu = ts / (float)D_DIM;
        float var = t2 / (float)D_DIM - mu * mu;
        float rs = rsqrtf(var + EPS_LN);
        xn[l * D_DIM + tid]       = (__hip_bfloat16)((v0 - mu) * rs * ln0w[tid] + ln0b[tid]);
        xn[l * D_DIM + 256 + tid] = (__hip_bfloat16)((v1 - mu) * rs * ln0w[256 + tid] + ln0b[256 + tid]);
        xb[l * D_DIM + tid]       = (__hip_bfloat16)v0;
        xb[l * D_DIM + 256 + tid] = (__hip_bfloat16)v1;
        return;
    }
    if (bid == 12544) {
        int e0 = tid * 16;
        float o1[16], o2[16];
#pragma unroll
        for (int j = 0; j < 16; ++j) {
            int ee = e0 + j;
            int pi = ((ee & 511) << 3) | (ee >> 9);
            o1[j] = ln1w[pi];
            o2[j] = ln1b[pi];
        }
#pragma unroll
        for (int j = 0; j < 4; ++j) {
            *(float4*)(wp + e0 + j * 4) = *(float4*)&o1[j * 4];
            *(float4*)(bp + e0 + j * 4) = *(float4*)&o2[j * 4];
        }
        return;
    }
    const float* in;
    __hip_bfloat16* out;
    int R, C, mode = 0, t;
    if (bid < 1152)      { t = bid - 1024;  in = qw; out = qkwt;                      R = 512;  C = 256; }
    else if (bid < 1280) { t = bid - 1152;  in = kw; out = qkwt + (size_t)AH * D_DIM; R = 512;  C = 256; }
    else if (bid < 3328) { t = bid - 1280;  in = vw; out = vwt;  mode = 1;            R = 512;  C = 4096; }
    else if (bid < 11520){ t = bid - 3328;  in = w1; out = w1t;  mode = 2;            R = 4096; C = 2048; }
    else                 { t = bid - 11520; in = w2; out = w2t;                       R = 2048; C = 512; }
    int ctiles = C >> 5;
    int cx = t % ctiles, cy = t / ctiles;
    int tx = tid & 31, ti = tid >> 5;
    int r0 = cy * 32, c0 = cx * 32;
#pragma unroll
    for (int ii = 0; ii < 4; ++ii) {
        int rr = r0 + ti + ii * 8;
        if (mode == 2) rr = ((rr & 511) << 3) | (rr >> 9);  // w1 K-perm
        tt[ti + ii * 8][tx] = in[(size_t)rr * C + c0 + tx];
    }
    __syncthreads();
#pragma unroll
    for (int ii = 0; ii < 4; ++ii) {
        int c = c0 + ti + ii * 8;
        int orow = (mode == 1) ? (((c & 7) << 9) | (c >> 3)) : c;
        out[(size_t)orow * R + r0 + tx] = (__hip_bfloat16)tt[tx][ti + ii * 8];
    }
}

// ---------------------------------------------------------------------------
// Shared BK=128 MFMA core, templated on BN (64 or 32). BM fixed 64.
// ---------------------------------------------------------------------------
template <int BN>
__device__ __forceinline__ void gemm_core(const __hip_bfloat16* __restrict__ A,
                                          const __hip_bfloat16* __restrict__ Bt,
                                          int K, int bm, int bn, int k_beg, int k_end,
                                          __hip_bfloat16* As, __hip_bfloat16* Bs,
                                          floatx4 (&acc)[2][BN / 32]) {
    constexpr int NT = BN / 32;
    const int tid = threadIdx.x;
    const int w = tid >> 6, lane = tid & 63;
    const int wm = (w >> 1) * 32, wn = (w & 1) * (BN / 2);
    const int quad = lane >> 4, l16 = lane & 15;
    const int srow = tid >> 4, sslot = tid & 15;
    const int scg = sslot ^ srow;
    for (int k0 = k_beg; k0 < k_end; k0 += 128) {
        __syncthreads();
#pragma unroll
        for (int j = 0; j < 4; ++j)
            ASYNC_COPY16(A + (size_t)(bm + j * 16 + srow) * K + k0 + scg * 8,
                         As + j * 2048 + w * 512);
#pragma unroll
        for (int j = 0; j < BN / 16; ++j)
            ASYNC_COPY16(Bt + (size_t)(bn + j * 16 + srow) * K + k0 + scg * 8,
                         Bs + j * 2048 + w * 512);
        __syncthreads();
#pragma unroll
        for (int ks = 0; ks < 4; ++ks) {
            short8 af[2], bfr[NT];
#pragma unroll
            for (int mt = 0; mt < 2; ++mt) {
                int rr = wm + mt * 16 + l16;
                af[mt] = *(const short8*)(As + rr * 128 + (((ks * 4 + quad) ^ (rr & 15)) * 8));
            }
#pragma unroll
            for (int nt = 0; nt < NT; ++nt) {
                int rr = wn + nt * 16 + l16;
                bfr[nt] = *(const short8*)(Bs + rr * 128 + (((ks * 4 + quad) ^ (rr & 15)) * 8));
            }
#pragma unroll
            for (int mt = 0; mt < 2; ++mt)
#pragma unroll
                for (int nt = 0; nt < NT; ++nt)
                    acc[mt][nt] = __builtin_amdgcn_mfma_f32_16x16x32_bf16(
                        af[mt], bfr[nt], acc[mt][nt], 0, 0, 0);
        }
    }
}

// ---------------------------------------------------------------------------
// Fused q|k and v projections. v -> vT[h*512+d][l]; q,k -> [h][l][a] bf16.
// ---------------------------------------------------------------------------
__global__ __launch_bounds__(256) void qkv_gemm(const __hip_bfloat16* __restrict__ xn,
                                                const __hip_bfloat16* __restrict__ xb,
                                                const __hip_bfloat16* __restrict__ qkwt,
                                                const __hip_bfloat16* __restrict__ vwt,
                                                const float* __restrict__ qb,
                                                const float* __restrict__ kb,
                                                const float* __restrict__ vb,
                                                __hip_bfloat16* __restrict__ q2,
                                                __hip_bfloat16* __restrict__ k2,
                                                __hip_bfloat16* __restrict__ vT) {
    __shared__ __align__(16) __hip_bfloat16 As[64 * 128];
    __shared__ __align__(16) __hip_bfloat16 Bs[64 * 128];
    const int tid = threadIdx.x;
    const int w = tid >> 6, lane = tid & 63;
    const int wm = (w >> 1) * 32, wn = (w & 1) * 32;
    const int quad = lane >> 4, l16 = lane & 15;
    int bid = blockIdx.x;
    bool isv = bid < 1024;
    const __hip_bfloat16 *A, *Bt;
    int bx, by;
    if (isv) {
        int r = bid >> 3;
        bx = (bid & 7) * 8 + (r & 7);
        by = r >> 3;
        A = xb; Bt = vwt;
    } else {
        int b2 = bid - 1024;
        bx = b2 & 7; by = b2 >> 3;
        A = xn; Bt = qkwt;
    }
    const int bm = by * 64, bn = bx * 64;
    floatx4 acc[2][2];
#pragma unroll
    for (int i = 0; i < 2; ++i)
#pragma unroll
        for (int j = 0; j < 2; ++j) acc[i][j] = (floatx4)0.f;
    gemm_core<64>(A, Bt, D_DIM, bm, bn, 0, D_DIM, As, Bs, acc);
    if (isv) {
        __syncthreads();
        __hip_bfloat16* Ct = As;
#pragma unroll
        for (int mt = 0; mt < 2; ++mt)
#pragma unroll
            for (int nt = 0; nt < 2; ++nt) {
                int col = bn + wn + nt * 16 + l16;
                int bi = ((col & 511) << 3) | (col >> 9);
                float bbv = vb[bi];
                __hip_bfloat16 tmp[4];
#pragma unroll
                for (int r = 0; r < 4; ++r)
                    tmp[r] = (__hip_bfloat16)(acc[mt][nt][r] + bbv);
                *(short4v*)&Ct[(wn + nt * 16 + l16) * 72 + wm + mt * 16 + quad * 4] =
                    *(short4v*)tmp;
            }
        __syncthreads();
        int colloc = tid >> 2, seg = (tid & 3) * 16;
        short8 o0 = *(const short8*)&Ct[colloc * 72 + seg];
        short8 o1 = *(const short8*)&Ct[colloc * 72 + seg + 8];
        *(short8*)(vT + (size_t)(bn + colloc) * 1024 + bm + seg) = o0;
        *(short8*)(vT + (size_t)(bn + colloc) * 1024 + bm + seg + 8) = o1;
    } else {
        __syncthreads();
        __hip_bfloat16* q2t = As;  // [h][l 64][a 8]
        bool isq = bn < 256;
        const float* bias = isq ? qb : kb;
        int cb = isq ? bn : bn - 256;
#pragma unroll
        for (int mt = 0; mt < 2; ++mt)
#pragma unroll
            for (int nt = 0; nt < 2; ++nt) {
                int colloc = wn + nt * 16 + l16;
                float bb = bias[cb + colloc];
                int hh = colloc & 7, aa = colloc >> 3;
#pragma unroll
                for (int r = 0; r < 4; ++r) {
                    int rowloc = wm + mt * 16 + quad * 4 + r;
                    float val = expf(fminf(fmaxf(acc[mt][nt][r] + bb, -10.f), 10.f));
                    q2t[((hh * 64 + rowloc) << 3) + aa] = (__hip_bfloat16)val;
                }
            }
        __syncthreads();
        __hip_bfloat16* dst = isq ? q2 : k2;
        int a0 = cb >> 3;
#pragma unroll
        for (int j = 0; j < 2; ++j) {
            int p = tid + j * 256;
            int hh = p >> 6, ll = p & 63;
            short8 o = *(const short8*)&q2t[(hh * 64 + ll) << 3];
            *(short8*)(dst + (size_t)(hh * 1024 + bm + ll) * 32 + a0) = o;
        }
    }
}

// ---------------------------------------------------------------------------
// w1 GEMM: BM=64, BN=32, full K=4096, no split. grid 1024, XCD strip=8.
// h1 = bf16(relu(y @ w1t^T + b1)) written directly.
// ---------------------------------------------------------------------------
__global__ __launch_bounds__(256) void w1_gemm(const __hip_bfloat16* __restrict__ y,
                                               const __hip_bfloat16* __restrict__ w1t,
                                               const float* __restrict__ b1,
                                               __hip_bfloat16* __restrict__ h1) {
    __shared__ __align__(16) __hip_bfloat16 As[64 * 128];
    __shared__ __align__(16) __hip_bfloat16 Bs[32 * 128];
    const int tid = threadIdx.x;
    const int w = tid >> 6, lane = tid & 63;
    const int wm = (w >> 1) * 32, wn = (w & 1) * 16;
    const int quad = lane >> 4, l16 = lane & 15;
    int bid = blockIdx.x;
    int r = bid >> 3;
    int bx = (bid & 7) * 8 + (r & 7);
    int by = r >> 3;
    const int bm = by * 64, bn = bx * 32;
    floatx4 acc[2][1];
    acc[0][0] = (floatx4)0.f;
    acc[1][0] = (floatx4)0.f;
    gemm_core<32>(y, w1t, DH, bm, bn, 0, DH, As, Bs, acc);
    int col = bn + wn + l16;
    float bb = b1[col];
#pragma unroll
    for (int mt = 0; mt < 2; ++mt)
#pragma unroll
        for (int rr = 0; rr < 4; ++rr) {
            int row = bm + wm + mt * 16 + quad * 4 + rr;
            h1[(size_t)row * F_DIM + col] =
                (__hip_bfloat16)fmaxf(acc[mt][0][rr] + bb, 0.f);
        }
}

// ---------------------------------------------------------------------------
// Split-K GEMM (w2) writing fp32 partials. STRIP: XCD swizzle.
// ---------------------------------------------------------------------------
template <int STRIP>
__global__ __launch_bounds__(256) void gemm_split(const __hip_bfloat16* __restrict__ A,
                                                  const __hip_bfloat16* __restrict__ Bt,
                                                  float* __restrict__ part,
                                                  int M, int N, int K, int Ksub) {
    __shared__ __align__(16) __hip_bfloat16 As[64 * 128];
    __shared__ __align__(16) __hip_bfloat16 Bs[64 * 128];
    const int tid = threadIdx.x;
    const int w = tid >> 6, lane = tid & 63;
    const int wm = (w >> 1) * 32, wn = (w & 1) * 32;
    const int quad = lane >> 4, l16 = lane & 15;
    int bid = blockIdx.x;
    int r = bid >> 3;
    int bx = (bid & 7) * STRIP + (r % STRIP);
    int by = r / STRIP;
    const int bm = by * 64, bn = bx * 64;
    const int kz = blockIdx.z;
    floatx4 acc[2][2];
#pragma unroll
    for (int i = 0; i < 2; ++i)
#pragma unroll
        for (int j = 0; j < 2; ++j) acc[i][j] = (floatx4)0.f;
    gemm_core<64>(A, Bt, K, bm, bn, kz * Ksub, kz * Ksub + Ksub, As, Bs, acc);
#pragma unroll
    for (int mt = 0; mt < 2; ++mt)
#pragma unroll
        for (int nt = 0; nt < 2; ++nt)
#pragma unroll
            for (int rr = 0; rr < 4; ++rr) {
                int row = bm + wm + mt * 16 + quad * 4 + rr;
                int col = bn + wn + nt * 16 + l16;
                part[((size_t)kz * M + row) * N + col] = acc[mt][nt][rr];
            }
}

__global__ __launch_bounds__(256) void w2red(const float* __restrict__ part,
                                             const float* __restrict__ b2,
                                             const float* __restrict__ x,
                                             float* __restrict__ out) {
    size_t e = ((size_t)blockIdx.x * 256 + threadIdx.x) * 4;
    const size_t MN = (size_t)L_SEQ * D_DIM;
    float4 v0 = *(const float4*)(part + e);
    float4 v1 = *(const float4*)(part + MN + e);
    float4 v2 = *(const float4*)(part + 2 * MN + e);
    float4 v3 = *(const float4*)(part + 3 * MN + e);
    float4 bb = *(const float4*)(b2 + (e & 511));
    float4 xx = *(const float4*)(x + e);
    float4 r;
    r.x = fmaxf(v0.x + v1.x + v2.x + v3.x + bb.x, 0.f) + xx.x;
    r.y = fmaxf(v0.y + v1.y + v2.y + v3.y + bb.y, 0.f) + xx.y;
    r.z = fmaxf(v0.z + v1.z + v2.z + v3.z + bb.z, 0.f) + xx.z;
    r.w = fmaxf(v0.w + v1.w + v2.w + v3.w + bb.w, 0.f) + xx.w;
    *(float4*)(out + e) = r;
}

// ---------------------------------------------------------------------------
// kvchunk (MFMA): S[c][h][d][a] = sum_l k2[h][c*64+l][a] * vT[h*512+d][c*64+l]
// ---------------------------------------------------------------------------
__global__ __launch_bounds__(256) void kvchunk_kernel(const __hip_bfloat16* __restrict__ k2,
                                                      const __hip_bfloat16* __restrict__ vT,
                                                      float* __restrict__ S,
                                                      float* __restrict__ Ka) {
    int c = blockIdx.x, h = blockIdx.y, dq = blockIdx.z;
    int tid = threadIdx.x;
    __shared__ __align__(16) __hip_bfloat16 kaT[32][72];
    __shared__ __align__(16) float St[128][36];
    {
        int l = tid >> 2, a0s = (tid & 3) * 8;
        short8 kv8 = *(const short8*)(k2 + (size_t)(h * 1024 + c * 64 + l) * 32 + a0s);
#pragma unroll
        for (int j = 0; j < 8; ++j)
            kaT[a0s + j][l] = ((const __hip_bfloat16*)&kv8)[j];
    }
    __syncthreads();
    int w = tid >> 6, lane = tid & 63, quad = lane >> 4, l16 = lane & 15;
    floatx4 acc[2][2];
#pragma unroll
    for (int i = 0; i < 2; ++i)
#pragma unroll
        for (int j = 0; j < 2; ++j) acc[i][j] = (floatx4)0.f;
#pragma unroll
    for (int ks = 0; ks < 2; ++ks) {
        short8 af[2], bfr[2];
#pragma unroll
        for (int mt = 0; mt < 2; ++mt)
            af[mt] = *(const short8*)&kaT[mt * 16 + l16][ks * 32 + quad * 8];
#pragma unroll
        for (int nt = 0; nt < 2; ++nt)
            bfr[nt] = *(const short8*)(vT + (size_t)(h * 512 + dq * 128 + w * 32 + nt * 16 + l16) * 1024
                                       + c * 64 + ks * 32 + quad * 8);
#pragma unroll
        for (int mt = 0; mt < 2; ++mt)
#pragma unroll
            for (int nt = 0; nt < 2; ++nt)
                acc[mt][nt] = __builtin_amdgcn_mfma_f32_16x16x32_bf16(
                    af[mt], bfr[nt], acc[mt][nt], 0, 0, 0);
    }
#pragma unroll
    for (int mt = 0; mt < 2; ++mt)
#pragma unroll
        for (int nt = 0; nt < 2; ++nt)
            *(floatx4*)&St[w * 32 + nt * 16 + l16][mt * 16 + quad * 4] = acc[mt][nt];
    __syncthreads();
    int d = tid >> 1, aseg = (tid & 1) * 16;
    float* dst = S + (size_t)((c * 8 + h) * 512 + dq * 128 + d) * 32 + aseg;
    const float* src = &St[d][aseg];
#pragma unroll
    for (int j = 0; j < 4; ++j)
        *(float4*)(dst + j * 4) = *(const float4*)(src + j * 4);
    if (dq == 0 && tid < 32) {
        float s = 0.f;
        for (int l = 0; l < CH; ++l) s += (float)kaT[tid][l];
        Ka[c * AH + tid * 8 + h] = s;
    }
}

// ---------------------------------------------------------------------------
// scan: element-wise exclusive chunk prefix (S fp32 -> P2 bf16), coalesced.
// ---------------------------------------------------------------------------
__global__ __launch_bounds__(256) void scan_kernel(const float* __restrict__ S,
                                                   const float* __restrict__ Ka,
                                                   __hip_bfloat16* __restrict__ P2,
                                                   float* __restrict__ KaP) {
    size_t j = ((size_t)blockIdx.x * 256 + threadIdx.x) * 4;
    const size_t CS = 8 * 512 * 32;
    float4 run = {0.f, 0.f, 0.f, 0.f};
    for (int c = 0; c < NC; ++c) {
        __hip_bfloat16 o[4] = {(__hip_bfloat16)run.x, (__hip_bfloat16)run.y,
                               (__hip_bfloat16)run.z, (__hip_bfloat16)run.w};
        *(short4v*)&P2[c * CS + j] = *(short4v*)o;
        float4 sv = *(const float4*)(S + c * CS + j);
        run.x += sv.x; run.y += sv.y; run.z += sv.z; run.w += sv.w;
    }
    if (blockIdx.x == 0) {
        int t = threadIdx.x;
        float rk = 0.f;
        for (int c = 0; c < NC; ++c) {
            KaP[c * AH + t] = rk;
            rk += Ka[c * AH + t];
        }
    }
}

// ---------------------------------------------------------------------------
// passC (MFMA): qkv = mask(Q K^T) V + Q P2 ; den = rowsum(mask) + q.KaP.
// ---------------------------------------------------------------------------
__global__ __launch_bounds__(256) void passC_kernel(const __hip_bfloat16* __restrict__ q2,
                                                    const __hip_bfloat16* __restrict__ k2,
                                                    const __hip_bfloat16* __restrict__ vT,
                                                    const __hip_bfloat16* __restrict__ P2,
                                                    const float* __restrict__ KaP,
                                                    __hip_bfloat16* __restrict__ qkv,
                                                    float* __restrict__ den) {
    int c = blockIdx.x, h = blockIdx.y, dq = blockIdx.z;
    int tid = threadIdx.x;
    __shared__ __align__(16) __hip_bfloat16 Sc[64][72];
    __shared__ float KaPs[32];
    if (dq == 0 && tid < 32) KaPs[tid] = KaP[c * AH + tid * 8 + h];
    int w = tid >> 6, lane = tid & 63, quad = lane >> 4, l16 = lane & 15;
    const size_t qbase = (size_t)(h * 1024 + c * 64) * 32;
    short8 afq = *(const short8*)(q2 + qbase + (w * 16 + l16) * 32 + quad * 8);
    floatx4 sacc[4];
#pragma unroll
    for (int nt = 0; nt < 4; ++nt) sacc[nt] = (floatx4)0.f;
#pragma unroll
    for (int nt = 0; nt < 4; ++nt) {
        short8 bfr = *(const short8*)(k2 + qbase + (nt * 16 + l16) * 32 + quad * 8);
        sacc[nt] = __builtin_amdgcn_mfma_f32_16x16x32_bf16(afq, bfr, sacc[nt], 0, 0, 0);
    }
#pragma unroll
    for (int nt = 0; nt < 4; ++nt)
#pragma unroll
        for (int r = 0; r < 4; ++r) {
            int l = w * 16 + quad * 4 + r;
            int lp = nt * 16 + l16;
            Sc[l][lp] = (__hip_bfloat16)((lp <= l) ? sacc[nt][r] : 0.f);
        }
    __syncthreads();
    if (dq == 0 && tid < 64) {
        int l = tid;
        float s = 0.f;
        for (int lp = 0; lp <= l; ++lp) s += (float)Sc[l][lp];
        const __hip_bfloat16* qp = q2 + qbase + l * 32;
        for (int a = 0; a < A_DIM; ++a) s += (float)qp[a] * KaPs[a];
        den[(c * CH + l) * H_DIM + h] = s;
    }
    floatx4 acc[8];
#pragma unroll
    for (int nt = 0; nt < 8; ++nt) acc[nt] = (floatx4)0.f;
#pragma unroll
    for (int nt = 0; nt < 8; ++nt) {
        short8 pb = *(const short8*)(P2 + ((size_t)((c * 8 + h) * 512 + dq * 128 + nt * 16 + l16)) * 32 + quad * 8);
        acc[nt] = __builtin_amdgcn_mfma_f32_16x16x32_bf16(afq, pb, acc[nt], 0, 0, 0);
    }
#pragma unroll
    for (int ks = 0; ks < 2; ++ks) {
        short8 afs = *(const short8*)&Sc[w * 16 + l16][ks * 32 + quad * 8];
#pragma unroll
        for (int nt = 0; nt < 8; ++nt) {
            short8 bfr = *(const short8*)(vT + (size_t)(h * 512 + dq * 128 + nt * 16 + l16) * 1024
                                          + c * 64 + ks * 32 + quad * 8);
            acc[nt] = __builtin_amdgcn_mfma_f32_16x16x32_bf16(afs, bfr, acc[nt], 0, 0, 0);
        }
    }
#pragma unroll
    for (int nt = 0; nt < 8; ++nt)
#pragma unroll
        for (int r = 0; r < 4; ++r) {
            int l = w * 16 + quad * 4 + r;
            int d = dq * 128 + nt * 16 + l16;
            qkv[(size_t)(c * CH + l) * DH + h * D_DIM + d] = (__hip_bfloat16)acc[nt][r];
        }
}

// ---------------------------------------------------------------------------
// LN1 over (D,H) + residual, fully vectorized (wp/bp pre-permuted).
// ---------------------------------------------------------------------------
__global__ __launch_bounds__(256) void ln1_kernel(const __hip_bfloat16* __restrict__ qkv,
                                                  const float* __restrict__ den,
                                                  const float* __restrict__ x,
                                                  const float* __restrict__ wp,
                                                  const float* __restrict__ bp,
                                                  __hip_bfloat16* __restrict__ y) {
    int l = blockIdx.x, tid = threadIdx.x;
    __shared__ float red[8];
    int h = tid >> 5;
    int e0 = tid * 16;
    int d0 = e0 & 511;
    float rden = 1.f / den[l * 8 + h];
    short8 v0 = *(const short8*)(qkv + (size_t)l * DH + e0);
    short8 v1 = *(const short8*)(qkv + (size_t)l * DH + e0 + 8);
    float vals[16];
    float s = 0.f, s2 = 0.f;
#pragma unroll
    for (int j = 0; j < 8; ++j) {
        vals[j] = (float)((const __hip_bfloat16*)&v0)[j] * rden;
        vals[8 + j] = (float)((const __hip_bfloat16*)&v1)[j] * rden;
    }
#pragma unroll
    for (int j = 0; j < 16; ++j) { s += vals[j]; s2 += vals[j] * vals[j]; }
    for (int off = 32; off > 0; off >>= 1) {
        s += __shfl_down(s, off);
        s2 += __shfl_down(s2, off);
    }
    int lane = tid & 63, wid = tid >> 6;
    if (lane == 0) { red[wid] = s; red[4 + wid] = s2; }
    __syncthreads();
    float ts = red[0] + red[1] + red[2] + red[3];
    float t2 = red[4] + red[5] + red[6] + red[7];
    float mu = ts / (float)DH;
    float var = t2 / (float)DH - mu * mu;
    float rs = rsqrtf(var + EPS_LN);
    __hip_bfloat16 o[16];
#pragma unroll
    for (int j4 = 0; j4 < 4; ++j4) {
        float4 xx = *(const float4*)(x + l * D_DIM + d0 + j4 * 4);
        float4 wv = *(const float4*)(wp + e0 + j4 * 4);
        float4 bv = *(const float4*)(bp + e0 + j4 * 4);
        o[j4 * 4 + 0] = (__hip_bfloat16)(xx.x + (vals[j4 * 4 + 0] - mu) * rs * wv.x + bv.x);
        o[j4 * 4 + 1] = (__hip_bfloat16)(xx.y + (vals[j4 * 4 + 1] - mu) * rs * wv.y + bv.y);
        o[j4 * 4 + 2] = (__hip_bfloat16)(xx.z + (vals[j4 * 4 + 2] - mu) * rs * wv.z + bv.z);
        o[j4 * 4 + 3] = (__hip_bfloat16)(xx.w + (vals[j4 * 4 + 3] - mu) * rs * wv.w + bv.w);
    }
    *(short8*)(y + (size_t)l * DH + e0) = *(short8*)&o[0];
    *(short8*)(y + (size_t)l * DH + e0 + 8) = *(short8*)&o[8];
}

// ---------------------------------------------------------------------------
// Launch
// ---------------------------------------------------------------------------
extern "C" void kernel_launch(void* const* d_in, const int* in_sizes, int n_in,
                              void* d_out, int out_size, void* d_ws, size_t ws_size,
                              hipStream_t stream) {
    const float* x     = (const float*)d_in[0];
    const float* ln0_w = (const float*)d_in[1];
    const float* ln0_b = (const float*)d_in[2];
    const float* ln1_w = (const float*)d_in[3];
    const float* ln1_b = (const float*)d_in[4];
    const float* qw    = (const float*)d_in[5];
    const float* qb    = (const float*)d_in[6];
    const float* kw    = (const float*)d_in[7];
    const float* kb    = (const float*)d_in[8];
    const float* vw    = (const float*)d_in[9];
    const float* vb    = (const float*)d_in[10];
    const float* w1    = (const float*)d_in[11];
    const float* b1    = (const float*)d_in[12];
    const float* w2    = (const float*)d_in[13];
    const float* b2    = (const float*)d_in[14];
    float* out = (float*)d_out;

    char* ws = (char*)d_ws;
    __hip_bfloat16* xn_bf = (__hip_bfloat16*)(ws + 0);         // 1 MB
    __hip_bfloat16* xbf   = (__hip_bfloat16*)(ws + 1048576);   // 1 MB
    __hip_bfloat16* qkwt  = (__hip_bfloat16*)(ws + 2097152);   // 0.5 MB
    __hip_bfloat16* vwt   = (__hip_bfloat16*)(ws + 2621440);   // 4 MB
    __hip_bfloat16* w1t   = (__hip_bfloat16*)(ws + 6815744);   // 16 MB (K-permuted)
    __hip_bfloat16* w2t   = (__hip_bfloat16*)(ws + 23592960);  // 2 MB
    __hip_bfloat16* q2    = (__hip_bfloat16*)(ws + 25690112);  // 512 KB [h][l][a]
    __hip_bfloat16* k2    = (__hip_bfloat16*)(ws + 26214400);  // 512 KB [h][l][a]
    __hip_bfloat16* vT    = (__hip_bfloat16*)(ws + 26738688);  // 8 MB [h*512+d][l]
    float* S              = (float*)(ws + 35127296);           // 8 MB [c][h][d][a]
    __hip_bfloat16* P2    = (__hip_bfloat16*)(ws + 43515904);  // 4 MB [c][h][d][a]
    __hip_bfloat16* qkvb  = (__hip_bfloat16*)(ws + 51904512);  // 8 MB
    float* Ka  = (float*)(ws + 60293120);                      // 16 KB
    float* KaP = (float*)(ws + 60309504);                      // 16 KB
    float* den = (float*)(ws + 60325888);                      // 32 KB
    float* wp  = (float*)(ws + 60358656);                      // 16 KB
    float* bp  = (float*)(ws + 60375040);                      // 16 KB
    __hip_bfloat16* y  = P2;                 // alias: P2 dead after passC
    __hip_bfloat16* h1 = (__hip_bfloat16*)S; // alias: S dead after scan
    float* w2part = (float*)qkvb;            // alias: qkvb dead after ln1

    prep_kernel<<<12545, 256, 0, stream>>>(x, ln0_w, ln0_b, ln1_w, ln1_b,
                                           qw, kw, vw, w1, w2,
                                           xn_bf, xbf, qkwt, vwt, w1t, w2t, wp, bp);
    qkv_gemm<<<1152, 256, 0, stream>>>(xn_bf, xbf, qkwt, vwt, qb, kb, vb, q2, k2, vT);
    kvchunk_kernel<<<dim3(NC, H_DIM, 4), 256, 0, stream>>>(k2, vT, S, Ka);
    scan_kernel<<<128, 256, 0, stream>>>(S, Ka, P2, KaP);
    passC_kernel<<<dim3(NC, H_DIM, 4), 256, 0, stream>>>(q2, k2, vT, P2, KaP, qkvb, den);
    ln1_kernel<<<L_SEQ, 256, 0, stream>>>(qkvb, den, x, wp, bp, y);
    // w1: BN=32, no split-K, direct relu+bias epilogue
    w1_gemm<<<1024, 256, 0, stream>>>(y, w1t, b1, h1);
    // w2: split-K=4
    gemm_split<1><<<dim3(128, 1, 4), 256, 0, stream>>>(h1, w2t, w2part,
                                                       L_SEQ, D_DIM, F_DIM, F_DIM / 4);
    w2red<<<(L_SEQ * D_DIM) / 1024, 256, 0, stream>>>(w2part, b2, x, out);

    (void)in_sizes; (void)n_in; (void)out_size; (void)ws_size;
}